// Round 1
// baseline (1020.799 us; speedup 1.0000x reference)
//
#include <hip/hip_runtime.h>

#define N_TOK 8192
#define DIM   1024
#define HID   4096
#define NEXP  4
#define MAXS  8192
#define BM 128
#define BN 128
#define BK 32

typedef __attribute__((ext_vector_type(8))) _Float16 f16x8;
typedef __attribute__((ext_vector_type(4))) float    f32x4;

__device__ __forceinline__ float gelu_erf(float v){
    return 0.5f * v * (1.0f + erff(v * 0.70710678118654752440f));
}

#define GLDS16(g, s) __builtin_amdgcn_global_load_lds( \
    (const __attribute__((address_space(1))) void*)(g), \
    (__attribute__((address_space(3))) void*)(s), 16, 0, 0)

// ---------------- init: zero counters + slot lists ----------------
__global__ void k_init(int* __restrict__ cnt, int* __restrict__ tokl, float* __restrict__ gatel){
    int i = blockIdx.x*256 + threadIdx.x;
    if (i < NEXP) cnt[i] = 0;
    if (i < NEXP*MAXS){ tokl[i] = 0; gatel[i] = 0.f; }
}

// ---------------- x -> f16 ----------------
__global__ void k_conv_x(const float* __restrict__ x, _Float16* __restrict__ xb, int n4){
    int i = blockIdx.x*256 + threadIdx.x;
    if (i >= n4) return;
    float4 v = ((const float4*)x)[i];
    f16x8 dummy; (void)dummy;
    _Float16 h0 = (_Float16)v.x, h1 = (_Float16)v.y, h2 = (_Float16)v.z, h3 = (_Float16)v.w;
    typedef __attribute__((ext_vector_type(4))) _Float16 f16x4;
    f16x4 h; h[0]=h0; h[1]=h1; h[2]=h2; h[3]=h3;
    ((f16x4*)xb)[i] = h;
}

// ---------------- transpose [R][C] f32 -> [C][R] f16 (per blockIdx.z matrix) ----------------
__global__ void k_transpose(const float* __restrict__ src, _Float16* __restrict__ dst, int R, int C){
    __shared__ float tile[32][33];
    const float* s = src + (size_t)blockIdx.z * R * C;
    _Float16*    d = dst + (size_t)blockIdx.z * R * C;
    int tx = threadIdx.x & 31, ty = threadIdx.x >> 5;   // 32 x 8
    int c0 = blockIdx.x*32, r0 = blockIdx.y*32;
    #pragma unroll
    for (int rr = 0; rr < 32; rr += 8)
        tile[ty+rr][tx] = s[(size_t)(r0+ty+rr)*C + c0+tx];
    __syncthreads();
    #pragma unroll
    for (int rr = 0; rr < 32; rr += 8)
        d[(size_t)(c0+ty+rr)*R + r0+tx] = (_Float16)tile[tx][ty+rr];
}

// ---------------- gelu(b1) ----------------
__global__ void k_gb1(const float* __restrict__ b1, float* __restrict__ gb1, int n){
    int i = blockIdx.x*256 + threadIdx.x;
    if (i < n) gb1[i] = gelu_erf(b1[i]);
}

// ---------------- c' partials: part[e][p][d] = sum_{h in p-th eighth} gelu(b1)[e][h]*w2[e][h][d]
__global__ void k_cprime_part(const float* __restrict__ w2, const float* __restrict__ gb1,
                              float* __restrict__ part){
    int d = blockIdx.x*256 + threadIdx.x;
    int p = blockIdx.y, e = blockIdx.z;
    float acc = 0.f;
    int h0 = p*(HID/8);
    for (int h = h0; h < h0 + HID/8; ++h)
        acc += gb1[e*HID + h] * w2[((size_t)e*HID + h)*DIM + d];
    part[(size_t)(e*8 + p)*DIM + d] = acc;
}

// ---------------- reduce partials -> cprime, csum ----------------
__global__ void k_cfinal(const float* __restrict__ part, const float* __restrict__ b2,
                         float* __restrict__ cprime, float* __restrict__ csum){
    int d = blockIdx.x*256 + threadIdx.x;
    float cs = 0.f;
    #pragma unroll
    for (int e = 0; e < NEXP; ++e){
        float a = 0.f;
        #pragma unroll
        for (int p = 0; p < 8; ++p) a += part[(size_t)(e*8 + p)*DIM + d];
        cprime[e*DIM + d] = a;
        cs += a + b2[e*DIM + d];
    }
    csum[d] = cs;
}

// ---------------- routing: logits, top-2, gates, compaction ----------------
__global__ void k_route(const float* __restrict__ x, const float* __restrict__ wr,
                        const float* __restrict__ br, int* __restrict__ expi,
                        float* __restrict__ gatev, int* __restrict__ cnt,
                        int* __restrict__ tokl, float* __restrict__ gatel){
    int lane = threadIdx.x & 63, w = threadIdx.x >> 6;
    int t = blockIdx.x*4 + w;
    float a0=0.f, a1=0.f, a2=0.f, a3=0.f;
    const float4* wr4 = (const float4*)wr;
    #pragma unroll
    for (int it = 0; it < 16; ++it){
        int d = it*64 + lane;
        float xv = x[(size_t)t*DIM + d];
        float4 wv = wr4[d];
        a0 += xv*wv.x; a1 += xv*wv.y; a2 += xv*wv.z; a3 += xv*wv.w;
    }
    #pragma unroll
    for (int off = 32; off; off >>= 1){
        a0 += __shfl_xor(a0, off);
        a1 += __shfl_xor(a1, off);
        a2 += __shfl_xor(a2, off);
        a3 += __shfl_xor(a3, off);
    }
    if (lane == 0){
        float v[4] = {a0+br[0], a1+br[1], a2+br[2], a3+br[3]};
        int e0 = 0; float v0 = v[0];
        #pragma unroll
        for (int e = 1; e < 4; ++e) if (v[e] > v0){ v0 = v[e]; e0 = e; }
        int e1 = -1; float v1 = -1e30f;
        #pragma unroll
        for (int e = 0; e < 4; ++e) if (e != e0 && v[e] > v1){ v1 = v[e]; e1 = e; }
        float ex = expf(v1 - v0);
        float g0 = 1.f/(1.f+ex), g1 = ex/(1.f+ex);
        expi[2*t] = e0; expi[2*t+1] = e1;
        gatev[2*t] = g0; gatev[2*t+1] = g1;
        int p0 = atomicAdd(&cnt[e0], 1); tokl[e0*MAXS+p0] = t; gatel[e0*MAXS+p0] = g0;
        int p1 = atomicAdd(&cnt[e1], 1); tokl[e1*MAXS+p1] = t; gatel[e1*MAXS+p1] = g1;
    }
}

// ---------------- out = csum - g0*c'[e0] - g1*c'[e1] ----------------
__global__ void k_bias(const int* __restrict__ expi, const float* __restrict__ gatev,
                       const float* __restrict__ cprime, const float* __restrict__ csum,
                       float* __restrict__ out){
    int i = blockIdx.x*256 + threadIdx.x;       // over N*D/4
    int t = i >> 8;                             // D/4 = 256
    int dq = i & 255;
    int e0 = expi[2*t], e1 = expi[2*t+1];
    float g0 = gatev[2*t], g1 = gatev[2*t+1];
    const float4* cp = (const float4*)cprime;
    float4 cs = ((const float4*)csum)[dq];
    float4 c0 = cp[e0*256 + dq], c1 = cp[e1*256 + dq];
    float4 r;
    r.x = cs.x - g0*c0.x - g1*c1.x;
    r.y = cs.y - g0*c0.y - g1*c1.y;
    r.z = cs.z - g0*c0.z - g1*c1.z;
    r.w = cs.w - g0*c0.w - g1*c1.w;
    ((float4*)out)[i] = r;
}

// ---------------- GEMM1: h[slot,:] = gelu(x[tok[slot]] @ W1_e + b1_e), f16 ----------------
__global__ __launch_bounds__(256)
void k_gemm1(const _Float16* __restrict__ xb, const _Float16* __restrict__ w1t,
             const float* __restrict__ b1, const int* __restrict__ tokl,
             const int* __restrict__ cnt, _Float16* __restrict__ hbuf, int e)
{
    __shared__ _Float16 As[2][BM*BK];
    __shared__ _Float16 Bs[2][BN*BK];
    const int mt = blockIdx.x, nt = blockIdx.y;
    if (mt*BM >= cnt[e]) return;
    const int tid = threadIdx.x;
    const int lane = tid & 63, w = tid >> 6;
    const int wr_ = w >> 1, wc = w & 1;
    const int srow = w*32 + (lane >> 2);
    const int kc   = (lane & 3) * 8;
    const int tok0 = tokl[e*MAXS + mt*BM + srow];
    const int tok1 = tokl[e*MAXS + mt*BM + srow + 16];
    const _Float16* gA0 = xb + (size_t)tok0*DIM + kc;
    const _Float16* gA1 = xb + (size_t)tok1*DIM + kc;
    const _Float16* gB0 = w1t + ((size_t)e*HID + (size_t)nt*BN + srow)*DIM + kc;
    const _Float16* gB1 = gB0 + (size_t)16*DIM;

    f32x4 acc[4][4];
    #pragma unroll
    for (int i = 0; i < 4; ++i)
        #pragma unroll
        for (int j = 0; j < 4; ++j) acc[i][j] = (f32x4){0.f,0.f,0.f,0.f};

    auto stage = [&](int cur, int kt){
        const int ko = kt*BK;
        GLDS16(gA0 + ko, &As[cur][(w*32)*BK]);
        GLDS16(gA1 + ko, &As[cur][(w*32+16)*BK]);
        GLDS16(gB0 + ko, &Bs[cur][(w*32)*BK]);
        GLDS16(gB1 + ko, &Bs[cur][(w*32+16)*BK]);
    };

    stage(0, 0);
    __syncthreads();
    const int NK = DIM/BK;
    const int lr = lane & 15, lk = lane >> 4;
    for (int kt = 0; kt < NK; ++kt){
        const int cur = kt & 1;
        if (kt + 1 < NK) stage(cur^1, kt+1);
        f16x8 a[4], b[4];
        #pragma unroll
        for (int i = 0; i < 4; ++i)
            a[i] = *(const f16x8*)&As[cur][(wr_*64 + i*16 + lr)*BK + lk*8];
        #pragma unroll
        for (int j = 0; j < 4; ++j)
            b[j] = *(const f16x8*)&Bs[cur][(wc*64 + j*16 + lr)*BK + lk*8];
        #pragma unroll
        for (int i = 0; i < 4; ++i)
            #pragma unroll
            for (int j = 0; j < 4; ++j)
                acc[i][j] = __builtin_amdgcn_mfma_f32_16x16x32_f16(a[i], b[j], acc[i][j], 0, 0, 0);
        __syncthreads();
    }
    // epilogue: + b1, gelu, f16 store
    #pragma unroll
    for (int j = 0; j < 4; ++j){
        int ncol = nt*BN + wc*64 + j*16 + lr;
        float bj = b1[e*HID + ncol];
        #pragma unroll
        for (int i = 0; i < 4; ++i){
            int sb = mt*BM + wr_*64 + i*16 + lk*4;
            #pragma unroll
            for (int r = 0; r < 4; ++r){
                float v = acc[i][j][r] + bj;
                hbuf[(size_t)(sb + r)*HID + ncol] = (_Float16)gelu_erf(v);
            }
        }
    }
}

// ---------------- GEMM2: out[tok[slot],:] += gate[slot] * (h[slot,:] @ W2_e) ----------------
__global__ __launch_bounds__(256)
void k_gemm2(const _Float16* __restrict__ hbuf, const _Float16* __restrict__ w2t,
             const int* __restrict__ tokl, const float* __restrict__ gatel,
             const int* __restrict__ cnt, float* __restrict__ out, int e)
{
    __shared__ _Float16 As[2][BM*BK];
    __shared__ _Float16 Bs[2][BN*BK];
    const int mt = blockIdx.x, nt = blockIdx.y;
    if (mt*BM >= cnt[e]) return;
    const int tid = threadIdx.x;
    const int lane = tid & 63, w = tid >> 6;
    const int wr_ = w >> 1, wc = w & 1;
    const int srow = w*32 + (lane >> 2);
    const int kc   = (lane & 3) * 8;
    const _Float16* gA0 = hbuf + (size_t)(mt*BM + srow)*HID + kc;
    const _Float16* gA1 = gA0 + (size_t)16*HID;
    const _Float16* gB0 = w2t + ((size_t)e*DIM + (size_t)nt*BN + srow)*HID + kc;
    const _Float16* gB1 = gB0 + (size_t)16*HID;

    f32x4 acc[4][4];
    #pragma unroll
    for (int i = 0; i < 4; ++i)
        #pragma unroll
        for (int j = 0; j < 4; ++j) acc[i][j] = (f32x4){0.f,0.f,0.f,0.f};

    auto stage = [&](int cur, int kt){
        const int ko = kt*BK;
        GLDS16(gA0 + ko, &As[cur][(w*32)*BK]);
        GLDS16(gA1 + ko, &As[cur][(w*32+16)*BK]);
        GLDS16(gB0 + ko, &Bs[cur][(w*32)*BK]);
        GLDS16(gB1 + ko, &Bs[cur][(w*32+16)*BK]);
    };

    stage(0, 0);
    __syncthreads();
    const int NK = HID/BK;
    const int lr = lane & 15, lk = lane >> 4;
    for (int kt = 0; kt < NK; ++kt){
        const int cur = kt & 1;
        if (kt + 1 < NK) stage(cur^1, kt+1);
        f16x8 a[4], b[4];
        #pragma unroll
        for (int i = 0; i < 4; ++i)
            a[i] = *(const f16x8*)&As[cur][(wr_*64 + i*16 + lr)*BK + lk*8];
        #pragma unroll
        for (int j = 0; j < 4; ++j)
            b[j] = *(const f16x8*)&Bs[cur][(wc*64 + j*16 + lr)*BK + lk*8];
        #pragma unroll
        for (int i = 0; i < 4; ++i)
            #pragma unroll
            for (int j = 0; j < 4; ++j)
                acc[i][j] = __builtin_amdgcn_mfma_f32_16x16x32_f16(a[i], b[j], acc[i][j], 0, 0, 0);
        __syncthreads();
    }
    // epilogue: gated scatter-accumulate into out (fp32)
    #pragma unroll
    for (int i = 0; i < 4; ++i){
        int sb = mt*BM + wr_*64 + i*16 + lk*4;
        #pragma unroll
        for (int r = 0; r < 4; ++r){
            int slot = sb + r;
            int t = tokl[e*MAXS + slot];
            float g = gatel[e*MAXS + slot];
            if (g != 0.f){
                #pragma unroll
                for (int j = 0; j < 4; ++j){
                    int ncol = nt*BN + wc*64 + j*16 + lr;
                    out[(size_t)t*DIM + ncol] += g * acc[i][j][r];
                }
            }
        }
    }
}

extern "C" void kernel_launch(void* const* d_in, const int* in_sizes, int n_in,
                              void* d_out, int out_size, void* d_ws, size_t ws_size,
                              hipStream_t stream){
    const float* x  = (const float*)d_in[0];
    const float* w1 = (const float*)d_in[1];
    const float* b1 = (const float*)d_in[2];
    const float* w2 = (const float*)d_in[3];
    const float* b2 = (const float*)d_in[4];
    const float* wr = (const float*)d_in[5];
    const float* br = (const float*)d_in[6];
    float* out = (float*)d_out;

    char* ws = (char*)d_ws;
    size_t o = 0;
    auto take = [&](size_t bytes)->char*{
        char* p = ws + o;
        o = (o + bytes + 255) & ~(size_t)255;
        return p;
    };
    _Float16* xb    = (_Float16*)take((size_t)N_TOK*DIM*2);        // 16.8 MB
    _Float16* w1t   = (_Float16*)take((size_t)NEXP*HID*DIM*2);     // 33.5 MB
    _Float16* w2t   = (_Float16*)take((size_t)NEXP*HID*DIM*2);     // 33.5 MB
    _Float16* hbuf  = (_Float16*)take((size_t)MAXS*HID*2);         // 67.1 MB
    float*    gb1   = (float*)take((size_t)NEXP*HID*4);
    float*    part  = (float*)take((size_t)NEXP*8*DIM*4);
    float*    cprime= (float*)take((size_t)NEXP*DIM*4);
    float*    csum  = (float*)take((size_t)DIM*4);
    int*      cnt   = (int*)take(256);
    int*      expi  = (int*)take((size_t)N_TOK*2*4);
    float*    gatev = (float*)take((size_t)N_TOK*2*4);
    int*      tokl  = (int*)take((size_t)NEXP*MAXS*4);
    float*    gatel = (float*)take((size_t)NEXP*MAXS*4);
    (void)ws_size; (void)in_sizes; (void)n_in; (void)out_size;     // total ~152 MB

    hipLaunchKernelGGL(k_init, dim3(NEXP*MAXS/256), dim3(256), 0, stream, cnt, tokl, gatel);
    hipLaunchKernelGGL(k_conv_x, dim3(N_TOK*DIM/4/256), dim3(256), 0, stream, x, xb, N_TOK*DIM/4);
    hipLaunchKernelGGL(k_transpose, dim3(HID/32, DIM/32, NEXP), dim3(256), 0, stream, w1, w1t, DIM, HID);
    hipLaunchKernelGGL(k_transpose, dim3(DIM/32, HID/32, NEXP), dim3(256), 0, stream, w2, w2t, HID, DIM);
    hipLaunchKernelGGL(k_gb1, dim3(NEXP*HID/256), dim3(256), 0, stream, b1, gb1, NEXP*HID);
    hipLaunchKernelGGL(k_cprime_part, dim3(DIM/256, 8, NEXP), dim3(256), 0, stream, w2, gb1, part);
    hipLaunchKernelGGL(k_cfinal, dim3(DIM/256), dim3(256), 0, stream, part, b2, cprime, csum);
    hipLaunchKernelGGL(k_route, dim3(N_TOK/4), dim3(256), 0, stream, x, wr, br, expi, gatev, cnt, tokl, gatel);
    hipLaunchKernelGGL(k_bias, dim3(N_TOK*DIM/4/256), dim3(256), 0, stream, expi, gatev, cprime, csum, out);
    for (int e = 0; e < NEXP; ++e){
        hipLaunchKernelGGL(k_gemm1, dim3(MAXS/BM, HID/BN), dim3(256), 0, stream,
                           xb, w1t, b1, tokl, cnt, hbuf, e);
        hipLaunchKernelGGL(k_gemm2, dim3(MAXS/BM, DIM/BN), dim3(256), 0, stream,
                           hbuf, w2t, tokl, gatel, cnt, out, e);
    }
}

// Round 2
// 842.797 us; speedup vs baseline: 1.2112x; 1.2112x over previous
//
#include <hip/hip_runtime.h>

#define N_TOK 8192
#define DIM   1024
#define HID   4096
#define NEXP  4
#define MAXS  8192
#define BM 128
#define BN 128
#define BK 32

typedef __attribute__((ext_vector_type(8))) _Float16 f16x8;
typedef __attribute__((ext_vector_type(4))) _Float16 f16x4;
typedef __attribute__((ext_vector_type(4))) float    f32x4;

__device__ __forceinline__ float gelu_erf(float v){
    return 0.5f * v * (1.0f + erff(v * 0.70710678118654752440f));
}

#define GLDS16(g, s) __builtin_amdgcn_global_load_lds( \
    (const __attribute__((address_space(1))) void*)(g), \
    (__attribute__((address_space(3))) void*)(s), 16, 0, 0)

// ---------------- init: zero counters + slot lists ----------------
__global__ void k_init(int* __restrict__ cnt, int* __restrict__ tokl, float* __restrict__ gatel){
    int i = blockIdx.x*256 + threadIdx.x;
    if (i < NEXP) cnt[i] = 0;
    if (i < NEXP*MAXS){ tokl[i] = 0; gatel[i] = 0.f; }
}

// ---------------- transpose [R][C] f32 -> [C][R] f16 (per blockIdx.z matrix) ----------------
__global__ void k_transpose(const float* __restrict__ src, _Float16* __restrict__ dst, int R, int C){
    __shared__ float tile[32][33];
    const float* s = src + (size_t)blockIdx.z * R * C;
    _Float16*    d = dst + (size_t)blockIdx.z * R * C;
    int tx = threadIdx.x & 31, ty = threadIdx.x >> 5;   // 32 x 8
    int c0 = blockIdx.x*32, r0 = blockIdx.y*32;
    #pragma unroll
    for (int rr = 0; rr < 32; rr += 8)
        tile[ty+rr][tx] = s[(size_t)(r0+ty+rr)*C + c0+tx];
    __syncthreads();
    #pragma unroll
    for (int rr = 0; rr < 32; rr += 8)
        d[(size_t)(c0+ty+rr)*R + r0+tx] = (_Float16)tile[tx][ty+rr];
}

// ---------------- gelu(b1) ----------------
__global__ void k_gb1(const float* __restrict__ b1, float* __restrict__ gb1, int n){
    int i = blockIdx.x*256 + threadIdx.x;
    if (i < n) gb1[i] = gelu_erf(b1[i]);
}

// ---------------- c' partials ----------------
__global__ void k_cprime_part(const float* __restrict__ w2, const float* __restrict__ gb1,
                              float* __restrict__ part){
    int d = blockIdx.x*256 + threadIdx.x;
    int p = blockIdx.y, e = blockIdx.z;
    float acc = 0.f;
    int h0 = p*(HID/8);
    for (int h = h0; h < h0 + HID/8; ++h)
        acc += gb1[e*HID + h] * w2[((size_t)e*HID + h)*DIM + d];
    part[(size_t)(e*8 + p)*DIM + d] = acc;
}

// ---------------- reduce partials -> cprime, csum ----------------
__global__ void k_cfinal(const float* __restrict__ part, const float* __restrict__ b2,
                         float* __restrict__ cprime, float* __restrict__ csum){
    int d = blockIdx.x*256 + threadIdx.x;
    float cs = 0.f;
    #pragma unroll
    for (int e = 0; e < NEXP; ++e){
        float a = 0.f;
        #pragma unroll
        for (int p = 0; p < 8; ++p) a += part[(size_t)(e*8 + p)*DIM + d];
        cprime[e*DIM + d] = a;
        cs += a + b2[e*DIM + d];
    }
    csum[d] = cs;
}

// ---------------- routing logits + x->f16 (atomic-free) ----------------
// one wave per token; float4 x loads; writes xb (f16), expi, gatev.
__global__ void k_route(const float* __restrict__ x, const float* __restrict__ wr,
                        const float* __restrict__ br, _Float16* __restrict__ xb,
                        int* __restrict__ expi, float* __restrict__ gatev){
    int lane = threadIdx.x & 63, w = threadIdx.x >> 6;
    int t = blockIdx.x*4 + w;
    const float4* x4  = (const float4*)(x + (size_t)t*DIM);
    const float4* wr4 = (const float4*)wr;               // wr[d][0..3]
    f16x4* xb4 = (f16x4*)(xb + (size_t)t*DIM);
    float a0=0.f, a1=0.f, a2=0.f, a3=0.f;
    #pragma unroll
    for (int it = 0; it < 4; ++it){
        int q = it*64 + lane;                            // quad index 0..255
        float4 v = x4[q];
        f16x4 h; h[0]=(_Float16)v.x; h[1]=(_Float16)v.y; h[2]=(_Float16)v.z; h[3]=(_Float16)v.w;
        xb4[q] = h;
        int d = q*4;
        float4 w0 = wr4[d], w1v = wr4[d+1], w2v = wr4[d+2], w3v = wr4[d+3];
        a0 += v.x*w0.x + v.y*w1v.x + v.z*w2v.x + v.w*w3v.x;
        a1 += v.x*w0.y + v.y*w1v.y + v.z*w2v.y + v.w*w3v.y;
        a2 += v.x*w0.z + v.y*w1v.z + v.z*w2v.z + v.w*w3v.z;
        a3 += v.x*w0.w + v.y*w1v.w + v.z*w2v.w + v.w*w3v.w;
    }
    #pragma unroll
    for (int off = 32; off; off >>= 1){
        a0 += __shfl_xor(a0, off);
        a1 += __shfl_xor(a1, off);
        a2 += __shfl_xor(a2, off);
        a3 += __shfl_xor(a3, off);
    }
    if (lane == 0){
        float v[4] = {a0+br[0], a1+br[1], a2+br[2], a3+br[3]};
        int e0 = 0; float v0 = v[0];
        #pragma unroll
        for (int e = 1; e < 4; ++e) if (v[e] > v0){ v0 = v[e]; e0 = e; }
        int e1 = -1; float v1 = -1e30f;
        #pragma unroll
        for (int e = 0; e < 4; ++e) if (e != e0 && v[e] > v1){ v1 = v[e]; e1 = e; }
        float ex = expf(v1 - v0);
        float g0 = 1.f/(1.f+ex), g1 = ex/(1.f+ex);
        expi[2*t] = e0; expi[2*t+1] = e1;
        gatev[2*t] = g0; gatev[2*t+1] = g1;
    }
}

// ---------------- compaction: one block per expert, prefix-scan ----------------
__global__ __launch_bounds__(1024)
void k_compact(const int* __restrict__ expi, const float* __restrict__ gatev,
               int* __restrict__ cnt, int* __restrict__ tokl, float* __restrict__ gatel){
    const int e = blockIdx.x;
    const int tid = threadIdx.x;              // 0..1023
    const int lane = tid & 63, wv = tid >> 6; // 16 waves
    __shared__ int wsum[16];
    const int base = tid*16;                  // 16 entries/thread over 2*N_TOK
    int c = 0;
    #pragma unroll
    for (int i = 0; i < 16; ++i)
        c += (expi[base+i] == e);
    // inclusive scan within wave
    int sc = c;
    #pragma unroll
    for (int off = 1; off < 64; off <<= 1){
        int tv = __shfl_up(sc, off);
        if (lane >= off) sc += tv;
    }
    if (lane == 63) wsum[wv] = sc;
    __syncthreads();
    int wbase = 0;
    for (int i = 0; i < wv; ++i) wbase += wsum[i];
    int myoff = wbase + sc - c;               // exclusive prefix
    #pragma unroll
    for (int i = 0; i < 16; ++i){
        int j = base + i;
        if (expi[j] == e){
            tokl[e*MAXS + myoff]  = j >> 1;
            gatel[e*MAXS + myoff] = gatev[j];
            myoff++;
        }
    }
    if (tid == 1023) cnt[e] = wbase + sc;
}

// ---------------- out = csum - g0*c'[e0] - g1*c'[e1] ----------------
__global__ void k_bias(const int* __restrict__ expi, const float* __restrict__ gatev,
                       const float* __restrict__ cprime, const float* __restrict__ csum,
                       float* __restrict__ out){
    int i = blockIdx.x*256 + threadIdx.x;       // over N*D/4
    int t = i >> 8;                             // D/4 = 256
    int dq = i & 255;
    int e0 = expi[2*t], e1 = expi[2*t+1];
    float g0 = gatev[2*t], g1 = gatev[2*t+1];
    const float4* cp = (const float4*)cprime;
    float4 cs = ((const float4*)csum)[dq];
    float4 c0 = cp[e0*256 + dq], c1 = cp[e1*256 + dq];
    float4 r;
    r.x = cs.x - g0*c0.x - g1*c1.x;
    r.y = cs.y - g0*c0.y - g1*c1.y;
    r.z = cs.z - g0*c0.z - g1*c1.z;
    r.w = cs.w - g0*c0.w - g1*c1.w;
    ((float4*)out)[i] = r;
}

// ---------------- GEMM1: h[slot,:] = gelu(x[tok[slot]] @ W1_e + b1_e), f16 ----------------
__global__ __launch_bounds__(256)
void k_gemm1(const _Float16* __restrict__ xb, const _Float16* __restrict__ w1t,
             const float* __restrict__ b1, const int* __restrict__ tokl,
             const int* __restrict__ cnt, _Float16* __restrict__ hbuf, int e)
{
    __shared__ _Float16 As[2][BM*BK];
    __shared__ _Float16 Bs[2][BN*BK];
    const int mt = blockIdx.x, nt = blockIdx.y;
    if (mt*BM >= cnt[e]) return;
    const int tid = threadIdx.x;
    const int lane = tid & 63, w = tid >> 6;
    const int wr_ = w >> 1, wc = w & 1;
    const int srow = w*32 + (lane >> 2);
    const int kc   = (lane & 3) * 8;
    const int tok0 = tokl[e*MAXS + mt*BM + srow];
    const int tok1 = tokl[e*MAXS + mt*BM + srow + 16];
    const _Float16* gA0 = xb + (size_t)tok0*DIM + kc;
    const _Float16* gA1 = xb + (size_t)tok1*DIM + kc;
    const _Float16* gB0 = w1t + ((size_t)e*HID + (size_t)nt*BN + srow)*DIM + kc;
    const _Float16* gB1 = gB0 + (size_t)16*DIM;

    f32x4 acc[4][4];
    #pragma unroll
    for (int i = 0; i < 4; ++i)
        #pragma unroll
        for (int j = 0; j < 4; ++j) acc[i][j] = (f32x4){0.f,0.f,0.f,0.f};

    auto stage = [&](int cur, int kt){
        const int ko = kt*BK;
        GLDS16(gA0 + ko, &As[cur][(w*32)*BK]);
        GLDS16(gA1 + ko, &As[cur][(w*32+16)*BK]);
        GLDS16(gB0 + ko, &Bs[cur][(w*32)*BK]);
        GLDS16(gB1 + ko, &Bs[cur][(w*32+16)*BK]);
    };

    stage(0, 0);
    __syncthreads();
    const int NK = DIM/BK;
    const int lr = lane & 15, lk = lane >> 4;
    for (int kt = 0; kt < NK; ++kt){
        const int cur = kt & 1;
        if (kt + 1 < NK) stage(cur^1, kt+1);
        f16x8 a[4], b[4];
        #pragma unroll
        for (int i = 0; i < 4; ++i)
            a[i] = *(const f16x8*)&As[cur][(wr_*64 + i*16 + lr)*BK + lk*8];
        #pragma unroll
        for (int j = 0; j < 4; ++j)
            b[j] = *(const f16x8*)&Bs[cur][(wc*64 + j*16 + lr)*BK + lk*8];
        #pragma unroll
        for (int i = 0; i < 4; ++i)
            #pragma unroll
            for (int j = 0; j < 4; ++j)
                acc[i][j] = __builtin_amdgcn_mfma_f32_16x16x32_f16(a[i], b[j], acc[i][j], 0, 0, 0);
        __syncthreads();
    }
    #pragma unroll
    for (int j = 0; j < 4; ++j){
        int ncol = nt*BN + wc*64 + j*16 + lr;
        float bj = b1[e*HID + ncol];
        #pragma unroll
        for (int i = 0; i < 4; ++i){
            int sb = mt*BM + wr_*64 + i*16 + lk*4;
            #pragma unroll
            for (int r = 0; r < 4; ++r){
                float v = acc[i][j][r] + bj;
                hbuf[(size_t)(sb + r)*HID + ncol] = (_Float16)gelu_erf(v);
            }
        }
    }
}

// ---------------- GEMM2: out[tok[slot],:] += gate[slot] * (h[slot,:] @ W2_e) ----------------
__global__ __launch_bounds__(256)
void k_gemm2(const _Float16* __restrict__ hbuf, const _Float16* __restrict__ w2t,
             const int* __restrict__ tokl, const float* __restrict__ gatel,
             const int* __restrict__ cnt, float* __restrict__ out, int e)
{
    __shared__ _Float16 As[2][BM*BK];
    __shared__ _Float16 Bs[2][BN*BK];
    const int mt = blockIdx.x, nt = blockIdx.y;
    if (mt*BM >= cnt[e]) return;
    const int tid = threadIdx.x;
    const int lane = tid & 63, w = tid >> 6;
    const int wr_ = w >> 1, wc = w & 1;
    const int srow = w*32 + (lane >> 2);
    const int kc   = (lane & 3) * 8;
    const _Float16* gA0 = hbuf + (size_t)(mt*BM + srow)*HID + kc;
    const _Float16* gA1 = gA0 + (size_t)16*HID;
    const _Float16* gB0 = w2t + ((size_t)e*DIM + (size_t)nt*BN + srow)*HID + kc;
    const _Float16* gB1 = gB0 + (size_t)16*HID;

    f32x4 acc[4][4];
    #pragma unroll
    for (int i = 0; i < 4; ++i)
        #pragma unroll
        for (int j = 0; j < 4; ++j) acc[i][j] = (f32x4){0.f,0.f,0.f,0.f};

    auto stage = [&](int cur, int kt){
        const int ko = kt*BK;
        GLDS16(gA0 + ko, &As[cur][(w*32)*BK]);
        GLDS16(gA1 + ko, &As[cur][(w*32+16)*BK]);
        GLDS16(gB0 + ko, &Bs[cur][(w*32)*BK]);
        GLDS16(gB1 + ko, &Bs[cur][(w*32+16)*BK]);
    };

    stage(0, 0);
    __syncthreads();
    const int NK = HID/BK;
    const int lr = lane & 15, lk = lane >> 4;
    for (int kt = 0; kt < NK; ++kt){
        const int cur = kt & 1;
        if (kt + 1 < NK) stage(cur^1, kt+1);
        f16x8 a[4], b[4];
        #pragma unroll
        for (int i = 0; i < 4; ++i)
            a[i] = *(const f16x8*)&As[cur][(wr_*64 + i*16 + lr)*BK + lk*8];
        #pragma unroll
        for (int j = 0; j < 4; ++j)
            b[j] = *(const f16x8*)&Bs[cur][(wc*64 + j*16 + lr)*BK + lk*8];
        #pragma unroll
        for (int i = 0; i < 4; ++i)
            #pragma unroll
            for (int j = 0; j < 4; ++j)
                acc[i][j] = __builtin_amdgcn_mfma_f32_16x16x32_f16(a[i], b[j], acc[i][j], 0, 0, 0);
        __syncthreads();
    }
    #pragma unroll
    for (int i = 0; i < 4; ++i){
        int sb = mt*BM + wr_*64 + i*16 + lk*4;
        #pragma unroll
        for (int r = 0; r < 4; ++r){
            int slot = sb + r;
            int t = tokl[e*MAXS + slot];
            float g = gatel[e*MAXS + slot];
            if (g != 0.f){
                #pragma unroll
                for (int j = 0; j < 4; ++j){
                    int ncol = nt*BN + wc*64 + j*16 + lr;
                    out[(size_t)t*DIM + ncol] += g * acc[i][j][r];
                }
            }
        }
    }
}

extern "C" void kernel_launch(void* const* d_in, const int* in_sizes, int n_in,
                              void* d_out, int out_size, void* d_ws, size_t ws_size,
                              hipStream_t stream){
    const float* x  = (const float*)d_in[0];
    const float* w1 = (const float*)d_in[1];
    const float* b1 = (const float*)d_in[2];
    const float* w2 = (const float*)d_in[3];
    const float* b2 = (const float*)d_in[4];
    const float* wr = (const float*)d_in[5];
    const float* br = (const float*)d_in[6];
    float* out = (float*)d_out;

    char* ws = (char*)d_ws;
    size_t o = 0;
    auto take = [&](size_t bytes)->char*{
        char* p = ws + o;
        o = (o + bytes + 255) & ~(size_t)255;
        return p;
    };
    _Float16* xb    = (_Float16*)take((size_t)N_TOK*DIM*2);        // 16.8 MB
    _Float16* w1t   = (_Float16*)take((size_t)NEXP*HID*DIM*2);     // 33.5 MB
    _Float16* w2t   = (_Float16*)take((size_t)NEXP*HID*DIM*2);     // 33.5 MB
    _Float16* hbuf  = (_Float16*)take((size_t)MAXS*HID*2);         // 67.1 MB
    float*    gb1   = (float*)take((size_t)NEXP*HID*4);
    float*    part  = (float*)take((size_t)NEXP*8*DIM*4);
    float*    cprime= (float*)take((size_t)NEXP*DIM*4);
    float*    csum  = (float*)take((size_t)DIM*4);
    int*      cnt   = (int*)take(256);
    int*      expi  = (int*)take((size_t)N_TOK*2*4);
    float*    gatev = (float*)take((size_t)N_TOK*2*4);
    int*      tokl  = (int*)take((size_t)NEXP*MAXS*4);
    float*    gatel = (float*)take((size_t)NEXP*MAXS*4);
    (void)ws_size; (void)in_sizes; (void)n_in; (void)out_size;     // total ~152 MB

    hipLaunchKernelGGL(k_init, dim3(NEXP*MAXS/256), dim3(256), 0, stream, cnt, tokl, gatel);
    hipLaunchKernelGGL(k_transpose, dim3(HID/32, DIM/32, NEXP), dim3(256), 0, stream, w1, w1t, DIM, HID);
    hipLaunchKernelGGL(k_transpose, dim3(DIM/32, HID/32, NEXP), dim3(256), 0, stream, w2, w2t, HID, DIM);
    hipLaunchKernelGGL(k_gb1, dim3(NEXP*HID/256), dim3(256), 0, stream, b1, gb1, NEXP*HID);
    hipLaunchKernelGGL(k_cprime_part, dim3(DIM/256, 8, NEXP), dim3(256), 0, stream, w2, gb1, part);
    hipLaunchKernelGGL(k_cfinal, dim3(DIM/256), dim3(256), 0, stream, part, b2, cprime, csum);
    hipLaunchKernelGGL(k_route, dim3(N_TOK/4), dim3(256), 0, stream, x, wr, br, xb, expi, gatev);
    hipLaunchKernelGGL(k_compact, dim3(NEXP), dim3(1024), 0, stream, expi, gatev, cnt, tokl, gatel);
    hipLaunchKernelGGL(k_bias, dim3(N_TOK*DIM/4/256), dim3(256), 0, stream, expi, gatev, cprime, csum, out);
    for (int e = 0; e < NEXP; ++e){
        hipLaunchKernelGGL(k_gemm1, dim3(MAXS/BM, HID/BN), dim3(256), 0, stream,
                           xb, w1t, b1, tokl, cnt, hbuf, e);
        hipLaunchKernelGGL(k_gemm2, dim3(MAXS/BM, DIM/BN), dim3(256), 0, stream,
                           hbuf, w2t, tokl, gatel, cnt, out, e);
    }
}

// Round 3
// 686.692 us; speedup vs baseline: 1.4865x; 1.2273x over previous
//
#include <hip/hip_runtime.h>

#define N_TOK 8192
#define DIM   1024
#define HID   4096
#define NEXP  4
#define MAXT  132            // max padded m-tiles: 128 + 4 alignment pads
#define BM 128
#define BN 128
#define BK 32

typedef __attribute__((ext_vector_type(8))) _Float16 f16x8;
typedef __attribute__((ext_vector_type(4))) _Float16 f16x4;
typedef __attribute__((ext_vector_type(4))) float    f32x4;

__device__ __forceinline__ float gelu_erf(float v){
    return 0.5f * v * (1.0f + erff(v * 0.70710678118654752440f));
}

#define GLDS16(g, s) __builtin_amdgcn_global_load_lds( \
    (const __attribute__((address_space(1))) void*)(g), \
    (__attribute__((address_space(3))) void*)(s), 16, 0, 0)

// ---------------- init: zero token list (padding slots gather token 0) ------
__global__ void k_init(int* __restrict__ tokl){
    int i = blockIdx.x*256 + threadIdx.x;
    if (i < MAXT*BM) tokl[i] = 0;
}

// ---------------- transpose [R][C] f32 -> [C][R] f16 (per blockIdx.z) -------
__global__ void k_transpose(const float* __restrict__ src, _Float16* __restrict__ dst, int R, int C){
    __shared__ float tile[32][33];
    const float* s = src + (size_t)blockIdx.z * R * C;
    _Float16*    d = dst + (size_t)blockIdx.z * R * C;
    int tx = threadIdx.x & 31, ty = threadIdx.x >> 5;   // 32 x 8
    int c0 = blockIdx.x*32, r0 = blockIdx.y*32;
    #pragma unroll
    for (int rr = 0; rr < 32; rr += 8)
        tile[ty+rr][tx] = s[(size_t)(r0+ty+rr)*C + c0+tx];
    __syncthreads();
    #pragma unroll
    for (int rr = 0; rr < 32; rr += 8)
        d[(size_t)(c0+ty+rr)*R + r0+tx] = (_Float16)tile[tx][ty+rr];
}

// ---------------- gelu(b1) ----------------
__global__ void k_gb1(const float* __restrict__ b1, float* __restrict__ gb1, int n){
    int i = blockIdx.x*256 + threadIdx.x;
    if (i < n) gb1[i] = gelu_erf(b1[i]);
}

// ---------------- c' partials ----------------
__global__ void k_cprime_part(const float* __restrict__ w2, const float* __restrict__ gb1,
                              float* __restrict__ part){
    int d = blockIdx.x*256 + threadIdx.x;
    int p = blockIdx.y, e = blockIdx.z;
    float acc = 0.f;
    int h0 = p*(HID/8);
    for (int h = h0; h < h0 + HID/8; ++h)
        acc += gb1[e*HID + h] * w2[((size_t)e*HID + h)*DIM + d];
    part[(size_t)(e*8 + p)*DIM + d] = acc;
}

// ---------------- reduce partials -> cprime, csum ----------------
__global__ void k_cfinal(const float* __restrict__ part, const float* __restrict__ b2,
                         float* __restrict__ cprime, float* __restrict__ csum){
    int d = blockIdx.x*256 + threadIdx.x;
    float cs = 0.f;
    #pragma unroll
    for (int e = 0; e < NEXP; ++e){
        float a = 0.f;
        #pragma unroll
        for (int p = 0; p < 8; ++p) a += part[(size_t)(e*8 + p)*DIM + d];
        cprime[e*DIM + d] = a;
        cs += a + b2[e*DIM + d];
    }
    csum[d] = cs;
}

// ---------------- routing logits + x->f16 (atomic-free) ----------------
__global__ void k_route(const float* __restrict__ x, const float* __restrict__ wr,
                        const float* __restrict__ br, _Float16* __restrict__ xb,
                        int* __restrict__ expi, float* __restrict__ gatev){
    int lane = threadIdx.x & 63, w = threadIdx.x >> 6;
    int t = blockIdx.x*4 + w;
    const float4* x4  = (const float4*)(x + (size_t)t*DIM);
    const float4* wr4 = (const float4*)wr;               // wr[d][0..3]
    f16x4* xb4 = (f16x4*)(xb + (size_t)t*DIM);
    float a0=0.f, a1=0.f, a2=0.f, a3=0.f;
    #pragma unroll
    for (int it = 0; it < 4; ++it){
        int q = it*64 + lane;                            // quad index 0..255
        float4 v = x4[q];
        f16x4 h; h[0]=(_Float16)v.x; h[1]=(_Float16)v.y; h[2]=(_Float16)v.z; h[3]=(_Float16)v.w;
        xb4[q] = h;
        int d = q*4;
        float4 w0 = wr4[d], w1v = wr4[d+1], w2v = wr4[d+2], w3v = wr4[d+3];
        a0 += v.x*w0.x + v.y*w1v.x + v.z*w2v.x + v.w*w3v.x;
        a1 += v.x*w0.y + v.y*w1v.y + v.z*w2v.y + v.w*w3v.y;
        a2 += v.x*w0.z + v.y*w1v.z + v.z*w2v.z + v.w*w3v.z;
        a3 += v.x*w0.w + v.y*w1v.w + v.z*w2v.w + v.w*w3v.w;
    }
    #pragma unroll
    for (int off = 32; off; off >>= 1){
        a0 += __shfl_xor(a0, off);
        a1 += __shfl_xor(a1, off);
        a2 += __shfl_xor(a2, off);
        a3 += __shfl_xor(a3, off);
    }
    if (lane == 0){
        float v[4] = {a0+br[0], a1+br[1], a2+br[2], a3+br[3]};
        int e0 = 0; float v0 = v[0];
        #pragma unroll
        for (int e = 1; e < 4; ++e) if (v[e] > v0){ v0 = v[e]; e0 = e; }
        int e1 = -1; float v1 = -1e30f;
        #pragma unroll
        for (int e = 0; e < 4; ++e) if (e != e0 && v[e] > v1){ v1 = v[e]; e1 = e; }
        float ex = expf(v1 - v0);
        float g0 = 1.f/(1.f+ex), g1 = ex/(1.f+ex);
        expi[2*t] = e0; expi[2*t+1] = e1;
        gatev[2*t] = g0; gatev[2*t+1] = g1;
    }
}

// ---------------- global compaction: 4 blocks, each redundantly histograms --
// all experts (identical tile-base prefix), then scan-writes its own expert's
// slots into the 128-aligned global slot space. No cross-block ordering.
__global__ __launch_bounds__(1024)
void k_compact(const int* __restrict__ expi, const float* __restrict__ gatev,
               int* __restrict__ tbase, int* __restrict__ tokl, int* __restrict__ slotof){
    const int e = blockIdx.x;
    const int tid = threadIdx.x, lane = tid & 63, wv = tid >> 6;
    __shared__ int w4[16][4];
    __shared__ int wsum[16];
    int c0=0,c1=0,c2=0,c3=0;
    const int base = tid*16;                  // 16 entries/thread over 2*N_TOK
    #pragma unroll
    for (int i = 0; i < 16; ++i){
        int v = expi[base+i];
        c0 += (v==0); c1 += (v==1); c2 += (v==2); c3 += (v==3);
    }
    int mysel = (e==0)?c0:(e==1)?c1:(e==2)?c2:c3;
    int r0=c0, r1=c1, r2=c2, r3=c3;
    #pragma unroll
    for (int off = 32; off; off >>= 1){
        r0 += __shfl_xor(r0,off); r1 += __shfl_xor(r1,off);
        r2 += __shfl_xor(r2,off); r3 += __shfl_xor(r3,off);
    }
    if (lane == 0){ w4[wv][0]=r0; w4[wv][1]=r1; w4[wv][2]=r2; w4[wv][3]=r3; }
    // inclusive scan of own-expert count within wave
    int sc = mysel;
    #pragma unroll
    for (int off = 1; off < 64; off <<= 1){
        int tv = __shfl_up(sc, off);
        if (lane >= off) sc += tv;
    }
    if (lane == 63) wsum[wv] = sc;
    __syncthreads();
    int t0=0,t1=0,t2=0,t3=0;
    #pragma unroll
    for (int i = 0; i < 16; ++i){ t0+=w4[i][0]; t1+=w4[i][1]; t2+=w4[i][2]; t3+=w4[i][3]; }
    int n0=(t0+127)>>7, n1=(t1+127)>>7, n2=(t2+127)>>7, n3=(t3+127)>>7;
    int tb1=n0, tb2=n0+n1, tb3=n0+n1+n2, tb4=n0+n1+n2+n3;
    int mybase = ((e==0)?0:(e==1)?tb1:(e==2)?tb2:tb3)*BM;
    int wbase = 0;
    for (int i = 0; i < wv; ++i) wbase += wsum[i];
    int myoff = mybase + wbase + sc - mysel;  // exclusive prefix, global slot
    #pragma unroll
    for (int i = 0; i < 16; ++i){
        int j = base + i;
        if (expi[j] == e){
            tokl[myoff]  = j >> 1;
            slotof[j] = myoff;
            myoff++;
        }
    }
    if (e == 0 && tid == 0){
        tbase[0]=0; tbase[1]=tb1; tbase[2]=tb2; tbase[3]=tb3; tbase[4]=tb4;
    }
}

// ---------------- GEMM1 (all experts): h[slot,:] = gelu(x[tok[slot]]@W1_e + b1_e)
__global__ __launch_bounds__(256)
void k_gemm1(const _Float16* __restrict__ xb, const _Float16* __restrict__ w1t,
             const float* __restrict__ b1, const int* __restrict__ tokl,
             const int* __restrict__ tb, _Float16* __restrict__ hbuf)
{
    __shared__ _Float16 As[2][BM*BK];
    __shared__ _Float16 Bs[2][BN*BK];
    const int mt = blockIdx.x, nt = blockIdx.y;
    if (mt >= tb[4]) return;
    const int e = (mt >= tb[1]) + (mt >= tb[2]) + (mt >= tb[3]);
    const int tid = threadIdx.x;
    const int lane = tid & 63, w = tid >> 6;
    const int wr_ = w >> 1, wc = w & 1;
    const int srow = w*32 + (lane >> 2);
    const int kc   = (lane & 3) * 8;
    const int tok0 = tokl[mt*BM + srow];
    const int tok1 = tokl[mt*BM + srow + 16];
    const _Float16* gA0 = xb + (size_t)tok0*DIM + kc;
    const _Float16* gA1 = xb + (size_t)tok1*DIM + kc;
    const _Float16* gB0 = w1t + ((size_t)e*HID + (size_t)nt*BN + srow)*DIM + kc;
    const _Float16* gB1 = gB0 + (size_t)16*DIM;

    f32x4 acc[4][4];
    #pragma unroll
    for (int i = 0; i < 4; ++i)
        #pragma unroll
        for (int j = 0; j < 4; ++j) acc[i][j] = (f32x4){0.f,0.f,0.f,0.f};

    auto stage = [&](int cur, int kt){
        const int ko = kt*BK;
        GLDS16(gA0 + ko, &As[cur][(w*32)*BK]);
        GLDS16(gA1 + ko, &As[cur][(w*32+16)*BK]);
        GLDS16(gB0 + ko, &Bs[cur][(w*32)*BK]);
        GLDS16(gB1 + ko, &Bs[cur][(w*32+16)*BK]);
    };

    stage(0, 0);
    __syncthreads();
    const int NK = DIM/BK;
    const int lr = lane & 15, lk = lane >> 4;
    for (int kt = 0; kt < NK; ++kt){
        const int cur = kt & 1;
        if (kt + 1 < NK) stage(cur^1, kt+1);
        f16x8 a[4], b[4];
        #pragma unroll
        for (int i = 0; i < 4; ++i)
            a[i] = *(const f16x8*)&As[cur][(wr_*64 + i*16 + lr)*BK + lk*8];
        #pragma unroll
        for (int j = 0; j < 4; ++j)
            b[j] = *(const f16x8*)&Bs[cur][(wc*64 + j*16 + lr)*BK + lk*8];
        #pragma unroll
        for (int i = 0; i < 4; ++i)
            #pragma unroll
            for (int j = 0; j < 4; ++j)
                acc[i][j] = __builtin_amdgcn_mfma_f32_16x16x32_f16(a[i], b[j], acc[i][j], 0, 0, 0);
        __syncthreads();
    }
    #pragma unroll
    for (int j = 0; j < 4; ++j){
        int ncol = nt*BN + wc*64 + j*16 + lr;
        float bj = b1[e*HID + ncol];
        #pragma unroll
        for (int i = 0; i < 4; ++i){
            int sb = mt*BM + wr_*64 + i*16 + lk*4;
            #pragma unroll
            for (int r = 0; r < 4; ++r){
                float v = acc[i][j][r] + bj;
                hbuf[(size_t)(sb + r)*HID + ncol] = (_Float16)gelu_erf(v);
            }
        }
    }
}

// ---------------- GEMM2 (all experts): ybuf[slot,:] = h[slot,:] @ W2_e ------
__global__ __launch_bounds__(256)
void k_gemm2(const _Float16* __restrict__ hbuf, const _Float16* __restrict__ w2t,
             const int* __restrict__ tb, _Float16* __restrict__ ybuf)
{
    __shared__ _Float16 As[2][BM*BK];
    __shared__ _Float16 Bs[2][BN*BK];
    const int mt = blockIdx.x, nt = blockIdx.y;
    if (mt >= tb[4]) return;
    const int e = (mt >= tb[1]) + (mt >= tb[2]) + (mt >= tb[3]);
    const int tid = threadIdx.x;
    const int lane = tid & 63, w = tid >> 6;
    const int wr_ = w >> 1, wc = w & 1;
    const int srow = w*32 + (lane >> 2);
    const int kc   = (lane & 3) * 8;
    const _Float16* gA0 = hbuf + (size_t)(mt*BM + srow)*HID + kc;
    const _Float16* gA1 = gA0 + (size_t)16*HID;
    const _Float16* gB0 = w2t + ((size_t)e*DIM + (size_t)nt*BN + srow)*HID + kc;
    const _Float16* gB1 = gB0 + (size_t)16*HID;

    f32x4 acc[4][4];
    #pragma unroll
    for (int i = 0; i < 4; ++i)
        #pragma unroll
        for (int j = 0; j < 4; ++j) acc[i][j] = (f32x4){0.f,0.f,0.f,0.f};

    auto stage = [&](int cur, int kt){
        const int ko = kt*BK;
        GLDS16(gA0 + ko, &As[cur][(w*32)*BK]);
        GLDS16(gA1 + ko, &As[cur][(w*32+16)*BK]);
        GLDS16(gB0 + ko, &Bs[cur][(w*32)*BK]);
        GLDS16(gB1 + ko, &Bs[cur][(w*32+16)*BK]);
    };

    stage(0, 0);
    __syncthreads();
    const int NK = HID/BK;
    const int lr = lane & 15, lk = lane >> 4;
    for (int kt = 0; kt < NK; ++kt){
        const int cur = kt & 1;
        if (kt + 1 < NK) stage(cur^1, kt+1);
        f16x8 a[4], b[4];
        #pragma unroll
        for (int i = 0; i < 4; ++i)
            a[i] = *(const f16x8*)&As[cur][(wr_*64 + i*16 + lr)*BK + lk*8];
        #pragma unroll
        for (int j = 0; j < 4; ++j)
            b[j] = *(const f16x8*)&Bs[cur][(wc*64 + j*16 + lr)*BK + lk*8];
        #pragma unroll
        for (int i = 0; i < 4; ++i)
            #pragma unroll
            for (int j = 0; j < 4; ++j)
                acc[i][j] = __builtin_amdgcn_mfma_f32_16x16x32_f16(a[i], b[j], acc[i][j], 0, 0, 0);
        __syncthreads();
    }
    #pragma unroll
    for (int i = 0; i < 4; ++i){
        int sb = mt*BM + wr_*64 + i*16 + lk*4;
        #pragma unroll
        for (int r = 0; r < 4; ++r){
            int slot = sb + r;
            #pragma unroll
            for (int j = 0; j < 4; ++j){
                int ncol = nt*BN + wc*64 + j*16 + lr;
                ybuf[(size_t)slot*DIM + ncol] = (_Float16)acc[i][j][r];
            }
        }
    }
}

// ---------------- final: out = csum + g0*(y0-c'0) + g1*(y1-c'1) -------------
__global__ void k_final(const int* __restrict__ expi, const float* __restrict__ gatev,
                        const int* __restrict__ slotof, const _Float16* __restrict__ ybuf,
                        const float* __restrict__ cprime, const float* __restrict__ csum,
                        float* __restrict__ out){
    int i = blockIdx.x*256 + threadIdx.x;       // over N*D/4
    int t = i >> 8;                             // D/4 = 256
    int dq = i & 255;
    int e0 = expi[2*t], e1 = expi[2*t+1];
    float g0 = gatev[2*t], g1 = gatev[2*t+1];
    int s0 = slotof[2*t], s1 = slotof[2*t+1];
    const float4* cp = (const float4*)cprime;
    float4 cs = ((const float4*)csum)[dq];
    float4 c0 = cp[e0*256 + dq], c1 = cp[e1*256 + dq];
    f16x4 y0 = ((const f16x4*)ybuf)[(size_t)s0*256 + dq];
    f16x4 y1 = ((const f16x4*)ybuf)[(size_t)s1*256 + dq];
    float4 r;
    r.x = cs.x + g0*((float)y0[0] - c0.x) + g1*((float)y1[0] - c1.x);
    r.y = cs.y + g0*((float)y0[1] - c0.y) + g1*((float)y1[1] - c1.y);
    r.z = cs.z + g0*((float)y0[2] - c0.z) + g1*((float)y1[2] - c1.z);
    r.w = cs.w + g0*((float)y0[3] - c0.w) + g1*((float)y1[3] - c1.w);
    ((float4*)out)[i] = r;
}

extern "C" void kernel_launch(void* const* d_in, const int* in_sizes, int n_in,
                              void* d_out, int out_size, void* d_ws, size_t ws_size,
                              hipStream_t stream){
    const float* x  = (const float*)d_in[0];
    const float* w1 = (const float*)d_in[1];
    const float* b1 = (const float*)d_in[2];
    const float* w2 = (const float*)d_in[3];
    const float* b2 = (const float*)d_in[4];
    const float* wr = (const float*)d_in[5];
    const float* br = (const float*)d_in[6];
    float* out = (float*)d_out;

    char* ws = (char*)d_ws;
    size_t o = 0;
    auto take = [&](size_t bytes)->char*{
        char* p = ws + o;
        o = (o + bytes + 255) & ~(size_t)255;
        return p;
    };
    _Float16* xb    = (_Float16*)take((size_t)N_TOK*DIM*2);        // 16.8 MB
    _Float16* w1t   = (_Float16*)take((size_t)NEXP*HID*DIM*2);     // 33.5 MB
    _Float16* w2t   = (_Float16*)take((size_t)NEXP*HID*DIM*2);     // 33.5 MB
    _Float16* hbuf  = (_Float16*)take((size_t)MAXT*BM*HID*2);      // 138.4 MB
    _Float16* ybuf  = (_Float16*)take((size_t)MAXT*BM*DIM*2);      // 34.6 MB
    float*    gb1   = (float*)take((size_t)NEXP*HID*4);
    float*    part  = (float*)take((size_t)NEXP*8*DIM*4);
    float*    cprime= (float*)take((size_t)NEXP*DIM*4);
    float*    csum  = (float*)take((size_t)DIM*4);
    int*      tbase = (int*)take(64);
    int*      expi  = (int*)take((size_t)N_TOK*2*4);
    float*    gatev = (float*)take((size_t)N_TOK*2*4);
    int*      slotof= (int*)take((size_t)N_TOK*2*4);
    int*      tokl  = (int*)take((size_t)MAXT*BM*4);
    (void)ws_size; (void)in_sizes; (void)n_in; (void)out_size;     // total ~257 MB

    hipLaunchKernelGGL(k_init, dim3(MAXT*BM/256), dim3(256), 0, stream, tokl);
    hipLaunchKernelGGL(k_transpose, dim3(HID/32, DIM/32, NEXP), dim3(256), 0, stream, w1, w1t, DIM, HID);
    hipLaunchKernelGGL(k_transpose, dim3(DIM/32, HID/32, NEXP), dim3(256), 0, stream, w2, w2t, HID, DIM);
    hipLaunchKernelGGL(k_gb1, dim3(NEXP*HID/256), dim3(256), 0, stream, b1, gb1, NEXP*HID);
    hipLaunchKernelGGL(k_cprime_part, dim3(DIM/256, 8, NEXP), dim3(256), 0, stream, w2, gb1, part);
    hipLaunchKernelGGL(k_cfinal, dim3(DIM/256), dim3(256), 0, stream, part, b2, cprime, csum);
    hipLaunchKernelGGL(k_route, dim3(N_TOK/4), dim3(256), 0, stream, x, wr, br, xb, expi, gatev);
    hipLaunchKernelGGL(k_compact, dim3(NEXP), dim3(1024), 0, stream, expi, gatev, tbase, tokl, slotof);
    hipLaunchKernelGGL(k_gemm1, dim3(MAXT, HID/BN), dim3(256), 0, stream,
                       xb, w1t, b1, tokl, tbase, hbuf);
    hipLaunchKernelGGL(k_gemm2, dim3(MAXT, DIM/BN), dim3(256), 0, stream,
                       hbuf, w2t, tbase, ybuf);
    hipLaunchKernelGGL(k_final, dim3(N_TOK*DIM/4/256), dim3(256), 0, stream,
                       expi, gatev, slotof, ybuf, cprime, csum, out);
}

// Round 4
// 597.061 us; speedup vs baseline: 1.7097x; 1.1501x over previous
//
#include <hip/hip_runtime.h>

#define N_TOK 8192
#define DIM   1024
#define HID   4096
#define NEXP  4
#define MAXT  132            // max padded m-tiles: 128 + 4 alignment pads
#define BM 128
#define BN 128
#define BK 32

typedef __attribute__((ext_vector_type(8))) _Float16 f16x8;
typedef __attribute__((ext_vector_type(4))) _Float16 f16x4;
typedef __attribute__((ext_vector_type(4))) float    f32x4;

__device__ __forceinline__ float gelu_erf(float v){
    return 0.5f * v * (1.0f + erff(v * 0.70710678118654752440f));
}

#define GLDS16(g, s) __builtin_amdgcn_global_load_lds( \
    (const __attribute__((address_space(1))) void*)(g), \
    (__attribute__((address_space(3))) void*)(s), 16, 0, 0)

// ---------------- init: zero token list (padding slots gather token 0) ------
__global__ void k_init(int* __restrict__ tokl){
    int i = blockIdx.x*256 + threadIdx.x;
    if (i < MAXT*BM) tokl[i] = 0;
}

// ---------------- transpose [R][C] f32 -> [C][R] f16 (per blockIdx.z) -------
__global__ void k_transpose(const float* __restrict__ src, _Float16* __restrict__ dst, int R, int C){
    __shared__ float tile[32][33];
    const float* s = src + (size_t)blockIdx.z * R * C;
    _Float16*    d = dst + (size_t)blockIdx.z * R * C;
    int tx = threadIdx.x & 31, ty = threadIdx.x >> 5;   // 32 x 8
    int c0 = blockIdx.x*32, r0 = blockIdx.y*32;
    #pragma unroll
    for (int rr = 0; rr < 32; rr += 8)
        tile[ty+rr][tx] = s[(size_t)(r0+ty+rr)*C + c0+tx];
    __syncthreads();
    #pragma unroll
    for (int rr = 0; rr < 32; rr += 8)
        d[(size_t)(c0+ty+rr)*R + r0+tx] = (_Float16)tile[tx][ty+rr];
}

// ---------------- gelu(b1) ----------------
__global__ void k_gb1(const float* __restrict__ b1, float* __restrict__ gb1, int n){
    int i = blockIdx.x*256 + threadIdx.x;
    if (i < n) gb1[i] = gelu_erf(b1[i]);
}

// ---------------- c' partials ----------------
__global__ void k_cprime_part(const float* __restrict__ w2, const float* __restrict__ gb1,
                              float* __restrict__ part){
    int d = blockIdx.x*256 + threadIdx.x;
    int p = blockIdx.y, e = blockIdx.z;
    float acc = 0.f;
    int h0 = p*(HID/8);
    for (int h = h0; h < h0 + HID/8; ++h)
        acc += gb1[e*HID + h] * w2[((size_t)e*HID + h)*DIM + d];
    part[(size_t)(e*8 + p)*DIM + d] = acc;
}

// ---------------- reduce partials -> cprime, csum ----------------
__global__ void k_cfinal(const float* __restrict__ part, const float* __restrict__ b2,
                         float* __restrict__ cprime, float* __restrict__ csum){
    int d = blockIdx.x*256 + threadIdx.x;
    float cs = 0.f;
    #pragma unroll
    for (int e = 0; e < NEXP; ++e){
        float a = 0.f;
        #pragma unroll
        for (int p = 0; p < 8; ++p) a += part[(size_t)(e*8 + p)*DIM + d];
        cprime[e*DIM + d] = a;
        cs += a + b2[e*DIM + d];
    }
    csum[d] = cs;
}

// ---------------- routing logits + x->f16 (atomic-free) ----------------
__global__ void k_route(const float* __restrict__ x, const float* __restrict__ wr,
                        const float* __restrict__ br, _Float16* __restrict__ xb,
                        int* __restrict__ expi, float* __restrict__ gatev){
    int lane = threadIdx.x & 63, w = threadIdx.x >> 6;
    int t = blockIdx.x*4 + w;
    const float4* x4  = (const float4*)(x + (size_t)t*DIM);
    const float4* wr4 = (const float4*)wr;               // wr[d][0..3]
    f16x4* xb4 = (f16x4*)(xb + (size_t)t*DIM);
    float a0=0.f, a1=0.f, a2=0.f, a3=0.f;
    #pragma unroll
    for (int it = 0; it < 4; ++it){
        int q = it*64 + lane;                            // quad index 0..255
        float4 v = x4[q];
        f16x4 h; h[0]=(_Float16)v.x; h[1]=(_Float16)v.y; h[2]=(_Float16)v.z; h[3]=(_Float16)v.w;
        xb4[q] = h;
        int d = q*4;
        float4 w0 = wr4[d], w1v = wr4[d+1], w2v = wr4[d+2], w3v = wr4[d+3];
        a0 += v.x*w0.x + v.y*w1v.x + v.z*w2v.x + v.w*w3v.x;
        a1 += v.x*w0.y + v.y*w1v.y + v.z*w2v.y + v.w*w3v.y;
        a2 += v.x*w0.z + v.y*w1v.z + v.z*w2v.z + v.w*w3v.z;
        a3 += v.x*w0.w + v.y*w1v.w + v.z*w2v.w + v.w*w3v.w;
    }
    #pragma unroll
    for (int off = 32; off; off >>= 1){
        a0 += __shfl_xor(a0, off);
        a1 += __shfl_xor(a1, off);
        a2 += __shfl_xor(a2, off);
        a3 += __shfl_xor(a3, off);
    }
    if (lane == 0){
        float v[4] = {a0+br[0], a1+br[1], a2+br[2], a3+br[3]};
        int e0 = 0; float v0 = v[0];
        #pragma unroll
        for (int e = 1; e < 4; ++e) if (v[e] > v0){ v0 = v[e]; e0 = e; }
        int e1 = -1; float v1 = -1e30f;
        #pragma unroll
        for (int e = 0; e < 4; ++e) if (e != e0 && v[e] > v1){ v1 = v[e]; e1 = e; }
        float ex = expf(v1 - v0);
        float g0 = 1.f/(1.f+ex), g1 = ex/(1.f+ex);
        expi[2*t] = e0; expi[2*t+1] = e1;
        gatev[2*t] = g0; gatev[2*t+1] = g1;
    }
}

// ---------------- global compaction: 4 blocks, redundant histograms ---------
__global__ __launch_bounds__(1024)
void k_compact(const int* __restrict__ expi, const float* __restrict__ gatev,
               int* __restrict__ tbase, int* __restrict__ tokl, int* __restrict__ slotof){
    const int e = blockIdx.x;
    const int tid = threadIdx.x, lane = tid & 63, wv = tid >> 6;
    __shared__ int w4[16][4];
    __shared__ int wsum[16];
    int c0=0,c1=0,c2=0,c3=0;
    const int base = tid*16;                  // 16 entries/thread over 2*N_TOK
    #pragma unroll
    for (int i = 0; i < 16; ++i){
        int v = expi[base+i];
        c0 += (v==0); c1 += (v==1); c2 += (v==2); c3 += (v==3);
    }
    int mysel = (e==0)?c0:(e==1)?c1:(e==2)?c2:c3;
    int r0=c0, r1=c1, r2=c2, r3=c3;
    #pragma unroll
    for (int off = 32; off; off >>= 1){
        r0 += __shfl_xor(r0,off); r1 += __shfl_xor(r1,off);
        r2 += __shfl_xor(r2,off); r3 += __shfl_xor(r3,off);
    }
    if (lane == 0){ w4[wv][0]=r0; w4[wv][1]=r1; w4[wv][2]=r2; w4[wv][3]=r3; }
    int sc = mysel;
    #pragma unroll
    for (int off = 1; off < 64; off <<= 1){
        int tv = __shfl_up(sc, off);
        if (lane >= off) sc += tv;
    }
    if (lane == 63) wsum[wv] = sc;
    __syncthreads();
    int t0=0,t1=0,t2=0,t3=0;
    #pragma unroll
    for (int i = 0; i < 16; ++i){ t0+=w4[i][0]; t1+=w4[i][1]; t2+=w4[i][2]; t3+=w4[i][3]; }
    int n0=(t0+127)>>7, n1=(t1+127)>>7, n2=(t2+127)>>7, n3=(t3+127)>>7;
    int tb1=n0, tb2=n0+n1, tb3=n0+n1+n2, tb4=n0+n1+n2+n3;
    int mybase = ((e==0)?0:(e==1)?tb1:(e==2)?tb2:tb3)*BM;
    int wbase = 0;
    for (int i = 0; i < wv; ++i) wbase += wsum[i];
    int myoff = mybase + wbase + sc - mysel;  // exclusive prefix, global slot
    #pragma unroll
    for (int i = 0; i < 16; ++i){
        int j = base + i;
        if (expi[j] == e){
            tokl[myoff]  = j >> 1;
            slotof[j] = myoff;
            myoff++;
        }
    }
    if (e == 0 && tid == 0){
        tbase[0]=0; tbase[1]=tb1; tbase[2]=tb2; tbase[3]=tb3; tbase[4]=tb4;
    }
}

// ---------------- GEMM1 (all experts, XCD-chunked 1-D grid) -----------------
// logical tile = mt*NT + nt, mt-major per XCD: the 32 nt-blocks of one mt run
// on the same XCD concurrently -> A-panel is fetched once into that L2.
__global__ __launch_bounds__(256)
void k_gemm1(const _Float16* __restrict__ xb, const _Float16* __restrict__ w1t,
             const float* __restrict__ b1, const int* __restrict__ tokl,
             const int* __restrict__ tb, _Float16* __restrict__ hbuf)
{
    __shared__ _Float16 As[2][BM*BK];
    __shared__ _Float16 Bs[2][BN*BK];
    const int NT = HID/BN;                       // 32
    const int nwg = MAXT*NT;                     // 4224, divisible by 8
    const int logical = (blockIdx.x & 7)*(nwg >> 3) + (blockIdx.x >> 3);
    const int mt = logical / NT, nt = logical % NT;
    if (mt >= tb[4]) return;
    const int e = (mt >= tb[1]) + (mt >= tb[2]) + (mt >= tb[3]);
    const int tid = threadIdx.x;
    const int lane = tid & 63, w = tid >> 6;
    const int wr_ = w >> 1, wc = w & 1;
    const int srow = w*32 + (lane >> 2);
    const int kc   = (lane & 3) * 8;
    const int tok0 = tokl[mt*BM + srow];
    const int tok1 = tokl[mt*BM + srow + 16];
    const _Float16* gA0 = xb + (size_t)tok0*DIM + kc;
    const _Float16* gA1 = xb + (size_t)tok1*DIM + kc;
    const _Float16* gB0 = w1t + ((size_t)e*HID + (size_t)nt*BN + srow)*DIM + kc;
    const _Float16* gB1 = gB0 + (size_t)16*DIM;

    f32x4 acc[4][4];
    #pragma unroll
    for (int i = 0; i < 4; ++i)
        #pragma unroll
        for (int j = 0; j < 4; ++j) acc[i][j] = (f32x4){0.f,0.f,0.f,0.f};

    auto stage = [&](int cur, int kt){
        const int ko = kt*BK;
        GLDS16(gA0 + ko, &As[cur][(w*32)*BK]);
        GLDS16(gA1 + ko, &As[cur][(w*32+16)*BK]);
        GLDS16(gB0 + ko, &Bs[cur][(w*32)*BK]);
        GLDS16(gB1 + ko, &Bs[cur][(w*32+16)*BK]);
    };

    stage(0, 0);
    __syncthreads();
    const int NK = DIM/BK;
    const int lr = lane & 15, lk = lane >> 4;
    for (int kt = 0; kt < NK; ++kt){
        const int cur = kt & 1;
        if (kt + 1 < NK) stage(cur^1, kt+1);
        f16x8 a[4], b[4];
        #pragma unroll
        for (int i = 0; i < 4; ++i)
            a[i] = *(const f16x8*)&As[cur][(wr_*64 + i*16 + lr)*BK + lk*8];
        #pragma unroll
        for (int j = 0; j < 4; ++j)
            b[j] = *(const f16x8*)&Bs[cur][(wc*64 + j*16 + lr)*BK + lk*8];
        #pragma unroll
        for (int i = 0; i < 4; ++i)
            #pragma unroll
            for (int j = 0; j < 4; ++j)
                acc[i][j] = __builtin_amdgcn_mfma_f32_16x16x32_f16(a[i], b[j], acc[i][j], 0, 0, 0);
        __syncthreads();
    }
    #pragma unroll
    for (int j = 0; j < 4; ++j){
        int ncol = nt*BN + wc*64 + j*16 + lr;
        float bj = b1[e*HID + ncol];
        #pragma unroll
        for (int i = 0; i < 4; ++i){
            int sb = mt*BM + wr_*64 + i*16 + lk*4;
            #pragma unroll
            for (int r = 0; r < 4; ++r){
                float v = acc[i][j][r] + bj;
                hbuf[(size_t)(sb + r)*HID + ncol] = (_Float16)gelu_erf(v);
            }
        }
    }
}

// ---------------- GEMM2 (all experts, XCD-chunked 1-D grid) -----------------
__global__ __launch_bounds__(256)
void k_gemm2(const _Float16* __restrict__ hbuf, const _Float16* __restrict__ w2t,
             const int* __restrict__ tb, _Float16* __restrict__ ybuf)
{
    __shared__ _Float16 As[2][BM*BK];
    __shared__ _Float16 Bs[2][BN*BK];
    const int NT = DIM/BN;                       // 8
    const int nwg = MAXT*NT;                     // 1056, divisible by 8
    const int logical = (blockIdx.x & 7)*(nwg >> 3) + (blockIdx.x >> 3);
    const int mt = logical / NT, nt = logical % NT;
    if (mt >= tb[4]) return;
    const int e = (mt >= tb[1]) + (mt >= tb[2]) + (mt >= tb[3]);
    const int tid = threadIdx.x;
    const int lane = tid & 63, w = tid >> 6;
    const int wr_ = w >> 1, wc = w & 1;
    const int srow = w*32 + (lane >> 2);
    const int kc   = (lane & 3) * 8;
    const _Float16* gA0 = hbuf + (size_t)(mt*BM + srow)*HID + kc;
    const _Float16* gA1 = gA0 + (size_t)16*HID;
    const _Float16* gB0 = w2t + ((size_t)e*DIM + (size_t)nt*BN + srow)*HID + kc;
    const _Float16* gB1 = gB0 + (size_t)16*HID;

    f32x4 acc[4][4];
    #pragma unroll
    for (int i = 0; i < 4; ++i)
        #pragma unroll
        for (int j = 0; j < 4; ++j) acc[i][j] = (f32x4){0.f,0.f,0.f,0.f};

    auto stage = [&](int cur, int kt){
        const int ko = kt*BK;
        GLDS16(gA0 + ko, &As[cur][(w*32)*BK]);
        GLDS16(gA1 + ko, &As[cur][(w*32+16)*BK]);
        GLDS16(gB0 + ko, &Bs[cur][(w*32)*BK]);
        GLDS16(gB1 + ko, &Bs[cur][(w*32+16)*BK]);
    };

    stage(0, 0);
    __syncthreads();
    const int NK = HID/BK;
    const int lr = lane & 15, lk = lane >> 4;
    for (int kt = 0; kt < NK; ++kt){
        const int cur = kt & 1;
        if (kt + 1 < NK) stage(cur^1, kt+1);
        f16x8 a[4], b[4];
        #pragma unroll
        for (int i = 0; i < 4; ++i)
            a[i] = *(const f16x8*)&As[cur][(wr_*64 + i*16 + lr)*BK + lk*8];
        #pragma unroll
        for (int j = 0; j < 4; ++j)
            b[j] = *(const f16x8*)&Bs[cur][(wc*64 + j*16 + lr)*BK + lk*8];
        #pragma unroll
        for (int i = 0; i < 4; ++i)
            #pragma unroll
            for (int j = 0; j < 4; ++j)
                acc[i][j] = __builtin_amdgcn_mfma_f32_16x16x32_f16(a[i], b[j], acc[i][j], 0, 0, 0);
        __syncthreads();
    }
    #pragma unroll
    for (int i = 0; i < 4; ++i){
        int sb = mt*BM + wr_*64 + i*16 + lk*4;
        #pragma unroll
        for (int r = 0; r < 4; ++r){
            int slot = sb + r;
            #pragma unroll
            for (int j = 0; j < 4; ++j){
                int ncol = nt*BN + wc*64 + j*16 + lr;
                ybuf[(size_t)slot*DIM + ncol] = (_Float16)acc[i][j][r];
            }
        }
    }
}

// ---------------- final: out = csum + g0*(y0-c'0) + g1*(y1-c'1) -------------
__global__ void k_final(const int* __restrict__ expi, const float* __restrict__ gatev,
                        const int* __restrict__ slotof, const _Float16* __restrict__ ybuf,
                        const float* __restrict__ cprime, const float* __restrict__ csum,
                        float* __restrict__ out){
    int i = blockIdx.x*256 + threadIdx.x;       // over N*D/4
    int t = i >> 8;                             // D/4 = 256
    int dq = i & 255;
    int e0 = expi[2*t], e1 = expi[2*t+1];
    float g0 = gatev[2*t], g1 = gatev[2*t+1];
    int s0 = slotof[2*t], s1 = slotof[2*t+1];
    const float4* cp = (const float4*)cprime;
    float4 cs = ((const float4*)csum)[dq];
    float4 c0 = cp[e0*256 + dq], c1 = cp[e1*256 + dq];
    f16x4 y0 = ((const f16x4*)ybuf)[(size_t)s0*256 + dq];
    f16x4 y1 = ((const f16x4*)ybuf)[(size_t)s1*256 + dq];
    float4 r;
    r.x = cs.x + g0*((float)y0[0] - c0.x) + g1*((float)y1[0] - c1.x);
    r.y = cs.y + g0*((float)y0[1] - c0.y) + g1*((float)y1[1] - c1.y);
    r.z = cs.z + g0*((float)y0[2] - c0.z) + g1*((float)y1[2] - c1.z);
    r.w = cs.w + g0*((float)y0[3] - c0.w) + g1*((float)y1[3] - c1.w);
    ((float4*)out)[i] = r;
}

extern "C" void kernel_launch(void* const* d_in, const int* in_sizes, int n_in,
                              void* d_out, int out_size, void* d_ws, size_t ws_size,
                              hipStream_t stream){
    const float* x  = (const float*)d_in[0];
    const float* w1 = (const float*)d_in[1];
    const float* b1 = (const float*)d_in[2];
    const float* w2 = (const float*)d_in[3];
    const float* b2 = (const float*)d_in[4];
    const float* wr = (const float*)d_in[5];
    const float* br = (const float*)d_in[6];
    float* out = (float*)d_out;

    char* ws = (char*)d_ws;
    size_t o = 0;
    auto take = [&](size_t bytes)->char*{
        char* p = ws + o;
        o = (o + bytes + 255) & ~(size_t)255;
        return p;
    };
    _Float16* xb    = (_Float16*)take((size_t)N_TOK*DIM*2);        // 16.8 MB
    _Float16* w1t   = (_Float16*)take((size_t)NEXP*HID*DIM*2);     // 33.5 MB
    _Float16* w2t   = (_Float16*)take((size_t)NEXP*HID*DIM*2);     // 33.5 MB
    _Float16* hbuf  = (_Float16*)take((size_t)MAXT*BM*HID*2);      // 138.4 MB
    _Float16* ybuf  = (_Float16*)take((size_t)MAXT*BM*DIM*2);      // 34.6 MB
    float*    gb1   = (float*)take((size_t)NEXP*HID*4);
    float*    part  = (float*)take((size_t)NEXP*8*DIM*4);
    float*    cprime= (float*)take((size_t)NEXP*DIM*4);
    float*    csum  = (float*)take((size_t)DIM*4);
    int*      tbase = (int*)take(64);
    int*      expi  = (int*)take((size_t)N_TOK*2*4);
    float*    gatev = (float*)take((size_t)N_TOK*2*4);
    int*      slotof= (int*)take((size_t)N_TOK*2*4);
    int*      tokl  = (int*)take((size_t)MAXT*BM*4);
    (void)ws_size; (void)in_sizes; (void)n_in; (void)out_size;     // total ~257 MB

    hipLaunchKernelGGL(k_init, dim3(MAXT*BM/256), dim3(256), 0, stream, tokl);
    hipLaunchKernelGGL(k_transpose, dim3(HID/32, DIM/32, NEXP), dim3(256), 0, stream, w1, w1t, DIM, HID);
    hipLaunchKernelGGL(k_transpose, dim3(DIM/32, HID/32, NEXP), dim3(256), 0, stream, w2, w2t, HID, DIM);
    hipLaunchKernelGGL(k_gb1, dim3(NEXP*HID/256), dim3(256), 0, stream, b1, gb1, NEXP*HID);
    hipLaunchKernelGGL(k_cprime_part, dim3(DIM/256, 8, NEXP), dim3(256), 0, stream, w2, gb1, part);
    hipLaunchKernelGGL(k_cfinal, dim3(DIM/256), dim3(256), 0, stream, part, b2, cprime, csum);
    hipLaunchKernelGGL(k_route, dim3(N_TOK/4), dim3(256), 0, stream, x, wr, br, xb, expi, gatev);
    hipLaunchKernelGGL(k_compact, dim3(NEXP), dim3(1024), 0, stream, expi, gatev, tbase, tokl, slotof);
    hipLaunchKernelGGL(k_gemm1, dim3(MAXT*(HID/BN)), dim3(256), 0, stream,
                       xb, w1t, b1, tokl, tbase, hbuf);
    hipLaunchKernelGGL(k_gemm2, dim3(MAXT*(DIM/BN)), dim3(256), 0, stream,
                       hbuf, w2t, tbase, ybuf);
    hipLaunchKernelGGL(k_final, dim3(N_TOK*DIM/4/256), dim3(256), 0, stream,
                       expi, gatev, slotof, ybuf, cprime, csum, out);
}

// Round 6
// 519.883 us; speedup vs baseline: 1.9635x; 1.1485x over previous
//
#include <hip/hip_runtime.h>

#define N_TOK 8192
#define DIM   1024
#define HID   4096
#define NEXP  4
#define MAXT  68             // max 256-row m-tiles: 64 + 4 alignment pads
#define NSLOT (MAXT*256)

typedef __attribute__((ext_vector_type(8))) _Float16 f16x8;
typedef __attribute__((ext_vector_type(4))) _Float16 f16x4;
typedef __attribute__((ext_vector_type(4))) float    f32x4;

__device__ __forceinline__ float gelu_erf(float v){
    return 0.5f * v * (1.0f + erff(v * 0.70710678118654752440f));
}
// tanh-form GELU for the hot epilogue: |diff vs erf| < ~1.5e-3
__device__ __forceinline__ float gelu_tanh(float v){
    float u = 0.7978845608028654f * v * (1.0f + 0.044715f * v * v);
    float e = __expf(2.0f * u);
    float t = 1.0f - 2.0f / (e + 1.0f);
    return 0.5f * v * (1.0f + t);
}

#define GLDS16(g, s) __builtin_amdgcn_global_load_lds( \
    (const __attribute__((address_space(1))) void*)(g), \
    (__attribute__((address_space(3))) void*)(s), 16, 0, 0)

#define BARRIER() do{ __builtin_amdgcn_s_barrier(); __builtin_amdgcn_sched_barrier(0); }while(0)
#define VMCNT6() asm volatile("s_waitcnt vmcnt(6)" ::: "memory")
#define VMCNT4() asm volatile("s_waitcnt vmcnt(4)" ::: "memory")
#define VMCNT0() asm volatile("s_waitcnt vmcnt(0)" ::: "memory")

// ---------------- init: zero token list (padding slots gather token 0) ------
__global__ void k_init(int* __restrict__ tokl){
    int i = blockIdx.x*256 + threadIdx.x;
    if (i < NSLOT) tokl[i] = 0;
}

// ---------------- transpose [R][C] f32 -> [C][R] f16 (per blockIdx.z) -------
__global__ void k_transpose(const float* __restrict__ src, _Float16* __restrict__ dst, int R, int C){
    __shared__ float tile[32][33];
    const float* s = src + (size_t)blockIdx.z * R * C;
    _Float16*    d = dst + (size_t)blockIdx.z * R * C;
    int tx = threadIdx.x & 31, ty = threadIdx.x >> 5;   // 32 x 8
    int c0 = blockIdx.x*32, r0 = blockIdx.y*32;
    #pragma unroll
    for (int rr = 0; rr < 32; rr += 8)
        tile[ty+rr][tx] = s[(size_t)(r0+ty+rr)*C + c0+tx];
    __syncthreads();
    #pragma unroll
    for (int rr = 0; rr < 32; rr += 8)
        d[(size_t)(c0+ty+rr)*R + r0+tx] = (_Float16)tile[tx][ty+rr];
}

// ---------------- gelu(b1) (erf form — must match reference c') -------------
__global__ void k_gb1(const float* __restrict__ b1, float* __restrict__ gb1, int n){
    int i = blockIdx.x*256 + threadIdx.x;
    if (i < n) gb1[i] = gelu_erf(b1[i]);
}

// ---------------- c' partials ----------------
__global__ void k_cprime_part(const float* __restrict__ w2, const float* __restrict__ gb1,
                              float* __restrict__ part){
    int d = blockIdx.x*256 + threadIdx.x;
    int p = blockIdx.y, e = blockIdx.z;
    float acc = 0.f;
    int h0 = p*(HID/8);
    for (int h = h0; h < h0 + HID/8; ++h)
        acc += gb1[e*HID + h] * w2[((size_t)e*HID + h)*DIM + d];
    part[(size_t)(e*8 + p)*DIM + d] = acc;
}

// ---------------- reduce partials -> cprime, csum ----------------
__global__ void k_cfinal(const float* __restrict__ part, const float* __restrict__ b2,
                         float* __restrict__ cprime, float* __restrict__ csum){
    int d = blockIdx.x*256 + threadIdx.x;
    float cs = 0.f;
    #pragma unroll
    for (int e = 0; e < NEXP; ++e){
        float a = 0.f;
        #pragma unroll
        for (int p = 0; p < 8; ++p) a += part[(size_t)(e*8 + p)*DIM + d];
        cprime[e*DIM + d] = a;
        cs += a + b2[e*DIM + d];
    }
    csum[d] = cs;
}

// ---------------- routing logits + x->f16 (atomic-free) ----------------
__global__ void k_route(const float* __restrict__ x, const float* __restrict__ wr,
                        const float* __restrict__ br, _Float16* __restrict__ xb,
                        int* __restrict__ expi, float* __restrict__ gatev){
    int lane = threadIdx.x & 63, w = threadIdx.x >> 6;
    int t = blockIdx.x*4 + w;
    const float4* x4  = (const float4*)(x + (size_t)t*DIM);
    const float4* wr4 = (const float4*)wr;               // wr[d][0..3]
    f16x4* xb4 = (f16x4*)(xb + (size_t)t*DIM);
    float a0=0.f, a1=0.f, a2=0.f, a3=0.f;
    #pragma unroll
    for (int it = 0; it < 4; ++it){
        int q = it*64 + lane;
        float4 v = x4[q];
        f16x4 h; h[0]=(_Float16)v.x; h[1]=(_Float16)v.y; h[2]=(_Float16)v.z; h[3]=(_Float16)v.w;
        xb4[q] = h;
        int d = q*4;
        float4 w0 = wr4[d], w1v = wr4[d+1], w2v = wr4[d+2], w3v = wr4[d+3];
        a0 += v.x*w0.x + v.y*w1v.x + v.z*w2v.x + v.w*w3v.x;
        a1 += v.x*w0.y + v.y*w1v.y + v.z*w2v.y + v.w*w3v.y;
        a2 += v.x*w0.z + v.y*w1v.z + v.z*w2v.z + v.w*w3v.z;
        a3 += v.x*w0.w + v.y*w1v.w + v.z*w2v.w + v.w*w3v.w;
    }
    #pragma unroll
    for (int off = 32; off; off >>= 1){
        a0 += __shfl_xor(a0, off);
        a1 += __shfl_xor(a1, off);
        a2 += __shfl_xor(a2, off);
        a3 += __shfl_xor(a3, off);
    }
    if (lane == 0){
        float v[4] = {a0+br[0], a1+br[1], a2+br[2], a3+br[3]};
        int e0 = 0; float v0 = v[0];
        #pragma unroll
        for (int e = 1; e < 4; ++e) if (v[e] > v0){ v0 = v[e]; e0 = e; }
        int e1 = -1; float v1 = -1e30f;
        #pragma unroll
        for (int e = 0; e < 4; ++e) if (e != e0 && v[e] > v1){ v1 = v[e]; e1 = e; }
        float ex = expf(v1 - v0);
        float g0 = 1.f/(1.f+ex), g1 = ex/(1.f+ex);
        expi[2*t] = e0; expi[2*t+1] = e1;
        gatev[2*t] = g0; gatev[2*t+1] = g1;
    }
}

// ---------------- global compaction: 256-row aligned expert segments --------
__global__ __launch_bounds__(1024)
void k_compact(const int* __restrict__ expi, const float* __restrict__ gatev,
               int* __restrict__ tbase, int* __restrict__ tokl, int* __restrict__ slotof){
    const int e = blockIdx.x;
    const int tid = threadIdx.x, lane = tid & 63, wv = tid >> 6;
    __shared__ int w4[16][4];
    __shared__ int wsum[16];
    int c0=0,c1=0,c2=0,c3=0;
    const int base = tid*16;                  // 16 entries/thread over 2*N_TOK
    #pragma unroll
    for (int i = 0; i < 16; ++i){
        int v = expi[base+i];
        c0 += (v==0); c1 += (v==1); c2 += (v==2); c3 += (v==3);
    }
    int mysel = (e==0)?c0:(e==1)?c1:(e==2)?c2:c3;
    int r0=c0, r1=c1, r2=c2, r3=c3;
    #pragma unroll
    for (int off = 32; off; off >>= 1){
        r0 += __shfl_xor(r0,off); r1 += __shfl_xor(r1,off);
        r2 += __shfl_xor(r2,off); r3 += __shfl_xor(r3,off);
    }
    if (lane == 0){ w4[wv][0]=r0; w4[wv][1]=r1; w4[wv][2]=r2; w4[wv][3]=r3; }
    int sc = mysel;
    #pragma unroll
    for (int off = 1; off < 64; off <<= 1){
        int tv = __shfl_up(sc, off);
        if (lane >= off) sc += tv;
    }
    if (lane == 63) wsum[wv] = sc;
    __syncthreads();
    int t0=0,t1=0,t2=0,t3=0;
    #pragma unroll
    for (int i = 0; i < 16; ++i){ t0+=w4[i][0]; t1+=w4[i][1]; t2+=w4[i][2]; t3+=w4[i][3]; }
    int n0=(t0+255)>>8, n1=(t1+255)>>8, n2=(t2+255)>>8, n3=(t3+255)>>8;
    int tb1=n0, tb2=n0+n1, tb3=n0+n1+n2, tb4=n0+n1+n2+n3;
    int mybase = ((e==0)?0:(e==1)?tb1:(e==2)?tb2:tb3)*256;
    int wbase = 0;
    for (int i = 0; i < wv; ++i) wbase += wsum[i];
    int myoff = mybase + wbase + sc - mysel;
    #pragma unroll
    for (int i = 0; i < 16; ++i){
        int j = base + i;
        if (expi[j] == e){
            tokl[myoff]  = j >> 1;
            slotof[j] = myoff;
            myoff++;
        }
    }
    if (e == 0 && tid == 0){
        tbase[0]=0; tbase[1]=tb1; tbase[2]=tb2; tbase[3]=tb3; tbase[4]=tb4;
    }
}

// ===================== 256x256x64 4-phase/K-tile grouped GEMM ===============
// 512 thr = 8 waves (2M x 4N), per-wave 128x64 out (8x4 16x16 frags).
// LDS 128 KiB: buf q at q*65536 {A[256][64]f16 @+0, B @+32768}.
// Half-tiles == read groups: A0 = rows 0-63 & 128-191 (rA0 of both wr2),
// A1 = rows 64-127 & 192-255; B0 = 32-row stripes wc4*64+0..31; B1 = +32..63.
// XOR swizzle: chunk c ^= (row&7), applied on stage SOURCE and ds_read addr.
// m201 ledger: halves staged 7 ahead of read (1/phase), vmcnt(6)/K-tile.

#define MFMA_Q(RA, RB, MB, NB) \
  _Pragma("unroll") for (int mf_ = 0; mf_ < 4; ++mf_) \
    _Pragma("unroll") for (int nf_ = 0; nf_ < 2; ++nf_) \
      _Pragma("unroll") for (int ks_ = 0; ks_ < 2; ++ks_) \
        acc[MB+mf_][NB+nf_] = __builtin_amdgcn_mfma_f32_16x16x32_f16( \
            RA[mf_][ks_], RB[nf_][ks_], acc[MB+mf_][NB+nf_], 0, 0, 0)

#define LDA_HALF(DST, MB, CUR) \
  _Pragma("unroll") for (int mf_ = 0; mf_ < 4; ++mf_) \
    _Pragma("unroll") for (int ks_ = 0; ks_ < 2; ++ks_) \
      DST[mf_][ks_] = *(const f16x8*)(smem + (CUR)*65536 + (rbA[MB+mf_] ^ (ks_<<6)))

#define LDB_HALF(DST, NB, CUR) \
  _Pragma("unroll") for (int nf_ = 0; nf_ < 2; ++nf_) \
    _Pragma("unroll") for (int ks_ = 0; ks_ < 2; ++ks_) \
      DST[nf_][ks_] = *(const f16x8*)(smem + (CUR)*65536 + (rbB[NB+nf_] ^ (ks_<<6)))

// stage half H of K-tile KTN of A/B into buffer Q (2 loads/wave each)
#define STAGE_A(Q, KTN, H) do{ \
    GLDS16(pA[0][H] + (size_t)(KTN)*64, smem + (Q)*65536 + dstA[0][H]); \
    GLDS16(pA[1][H] + (size_t)(KTN)*64, smem + (Q)*65536 + dstA[1][H]); }while(0)
#define STAGE_B(Q, KTN, H) do{ \
    GLDS16(pB[0][H] + (size_t)(KTN)*64, smem + (Q)*65536 + 32768 + dstB[0][H]); \
    GLDS16(pB[1][H] + (size_t)(KTN)*64, smem + (Q)*65536 + 32768 + dstB[1][H]); }while(0)

template<int KDIM, int NDIM, bool G1>
__global__ __launch_bounds__(512, 2)
void k_gemm8(const _Float16* __restrict__ Aglob, const _Float16* __restrict__ Bglob,
             const float* __restrict__ b1, const int* __restrict__ tokl,
             const int* __restrict__ tb, _Float16* __restrict__ Cout)
{
    extern __shared__ char smem[];
    const int NT = NDIM/256;
    const int nwg = MAXT*NT;                     // divisible by 8
    const int logical = ((int)blockIdx.x & 7)*(nwg>>3) + ((int)blockIdx.x >> 3);
    const int mt = logical / NT, nt = logical % NT;
    if (mt >= tb[4]) return;
    const int e = (mt >= tb[1]) + (mt >= tb[2]) + (mt >= tb[3]);
    const int tid = (int)threadIdx.x;
    const int ln = tid & 63, wv = tid >> 6;
    const int wr2 = wv >> 2, wc4 = wv & 3;
    const int lr = ln & 15, lk = ln >> 4;
    const int NK = KDIM/64;

    // --- stage pointers: pX[l][h] + lane-uniform LDS dest offsets dstX[l][h]
    const _Float16* pA[2][2]; const _Float16* pB[2][2];
    int dstA[2][2], dstB[2][2];
    #pragma unroll
    for (int l = 0; l < 2; ++l)
      #pragma unroll
      for (int h = 0; h < 2; ++h){
        const int ch   = wv*2 + l;          // chunk 0..15 of the 16KB half
        const int flat = ch*64 + ln;        // 0..1023
        const int lr_  = flat >> 3;         // local row 0..127
        const int c    = flat & 7;          // physical 16B chunk in row
        const int csw  = (c ^ (lr_ & 7)) * 8;   // swizzled source col (f16)
        // A half rows: {0-63,128-191} (h=0) / {64-127,192-255} (h=1)
        const int rowA = (lr_ & 63) + ((lr_ >> 6) << 7) + h*64;
        // B half rows: stripes of 32 within each 64-row wave segment
        const int rowB = (lr_ & 31) + ((lr_ >> 5) << 6) + h*32;
        size_t arow;
        if constexpr (G1) arow = (size_t)tokl[mt*256 + rowA];
        else              arow = (size_t)(mt*256 + rowA);
        pA[l][h] = Aglob + arow*KDIM + csw;
        pB[l][h] = Bglob + ((size_t)e*NDIM + nt*256 + rowB)*KDIM + csw;
        const int lrs = ch*8;               // chunk's first local row
        dstA[l][h] = ((lrs & 63) + ((lrs >> 6) << 7) + h*64) * 128;
        dstB[l][h] = ((lrs & 31) + ((lrs >> 5) << 6) + h*32) * 128;
      }

    // --- ds_read swizzled base offsets
    int rbA[8], rbB[4];
    #pragma unroll
    for (int mf = 0; mf < 8; ++mf){
        int row = wr2*128 + mf*16 + lr;
        rbA[mf] = row*128 + ((lk*16) ^ ((row&7)<<4));
    }
    #pragma unroll
    for (int nf = 0; nf < 4; ++nf){
        int row = wc4*64 + nf*16 + lr;
        rbB[nf] = 32768 + row*128 + ((lk*16) ^ ((row&7)<<4));
    }

    f32x4 acc[8][4];
    #pragma unroll
    for (int i = 0; i < 8; ++i)
        #pragma unroll
        for (int j = 0; j < 4; ++j) acc[i][j] = (f32x4){0.f,0.f,0.f,0.f};
    f16x8 rA0[4][2], rA1[4][2], rB0[2][2], rB1[2][2];

    // --- prologue: 7 halves (tile0: A0,B0,B1,A1; tile1: A0,B0,B1)
    STAGE_A(0,0,0); STAGE_B(0,0,0); STAGE_B(0,0,1); STAGE_A(0,0,1);
    VMCNT4();
    STAGE_A(1,1,0); STAGE_B(1,1,0); STAGE_B(1,1,1);
    VMCNT6();
    BARRIER();

    for (int t = 0; t < NK; ++t){
        const int cur = t & 1, nxt = cur ^ 1;
        // phase 1: read A0,B0 (12) | stage A1 of t+1 -> nxt | mfma q(0,0)
        LDA_HALF(rA0, 0, cur); LDB_HALF(rB0, 0, cur);
        if (t+1 < NK) STAGE_A(nxt, t+1, 1);
        BARRIER();
        __builtin_amdgcn_s_setprio(1); MFMA_Q(rA0, rB0, 0, 0); __builtin_amdgcn_s_setprio(0);
        BARRIER();
        // phase 2: read B1 (4) | stage A0 of t+2 -> cur | mfma q(0,1)
        LDB_HALF(rB1, 2, cur);
        if (t+2 < NK) STAGE_A(cur, t+2, 0);
        BARRIER();
        __builtin_amdgcn_s_setprio(1); MFMA_Q(rA0, rB1, 0, 2); __builtin_amdgcn_s_setprio(0);
        BARRIER();
        // phase 3: read A1 (8) | stage B0 of t+2 -> cur | mfma q(1,1)
        LDA_HALF(rA1, 4, cur);
        if (t+2 < NK) STAGE_B(cur, t+2, 0);
        BARRIER();
        __builtin_amdgcn_s_setprio(1); MFMA_Q(rA1, rB1, 4, 2); __builtin_amdgcn_s_setprio(0);
        BARRIER();
        // phase 4: stage B1 of t+2 -> cur | vmcnt | mfma q(1,0)
        if (t+2 < NK){ STAGE_B(cur, t+2, 1); VMCNT6(); } else { VMCNT0(); }
        BARRIER();
        __builtin_amdgcn_s_setprio(1); MFMA_Q(rA1, rB0, 4, 0); __builtin_amdgcn_s_setprio(0);
        BARRIER();
    }

    // --- epilogue
    if constexpr (G1){
        float bv[4];
        #pragma unroll
        for (int nf = 0; nf < 4; ++nf)
            bv[nf] = b1[e*NDIM + nt*256 + wc4*64 + nf*16 + lr];
        #pragma unroll
        for (int mf = 0; mf < 8; ++mf){
            int row = mt*256 + wr2*128 + mf*16 + lk*4;
            #pragma unroll
            for (int nf = 0; nf < 4; ++nf){
                int col = nt*256 + wc4*64 + nf*16 + lr;
                #pragma unroll
                for (int r = 0; r < 4; ++r)
                    Cout[(size_t)(row+r)*NDIM + col] = (_Float16)gelu_tanh(acc[mf][nf][r] + bv[nf]);
            }
        }
    } else {
        #pragma unroll
        for (int mf = 0; mf < 8; ++mf){
            int row = mt*256 + wr2*128 + mf*16 + lk*4;
            #pragma unroll
            for (int nf = 0; nf < 4; ++nf){
                int col = nt*256 + wc4*64 + nf*16 + lr;
                #pragma unroll
                for (int r = 0; r < 4; ++r)
                    Cout[(size_t)(row+r)*NDIM + col] = (_Float16)acc[mf][nf][r];
            }
        }
    }
}

// ---------------- final: out = csum + g0*(y0-c'0) + g1*(y1-c'1) -------------
__global__ void k_final(const int* __restrict__ expi, const float* __restrict__ gatev,
                        const int* __restrict__ slotof, const _Float16* __restrict__ ybuf,
                        const float* __restrict__ cprime, const float* __restrict__ csum,
                        float* __restrict__ out){
    int i = blockIdx.x*256 + threadIdx.x;       // over N*D/4
    int t = i >> 8;                             // D/4 = 256
    int dq = i & 255;
    int e0 = expi[2*t], e1 = expi[2*t+1];
    float g0 = gatev[2*t], g1 = gatev[2*t+1];
    int s0 = slotof[2*t], s1 = slotof[2*t+1];
    const float4* cp = (const float4*)cprime;
    float4 cs = ((const float4*)csum)[dq];
    float4 c0 = cp[e0*256 + dq], c1 = cp[e1*256 + dq];
    f16x4 y0 = ((const f16x4*)ybuf)[(size_t)s0*256 + dq];
    f16x4 y1 = ((const f16x4*)ybuf)[(size_t)s1*256 + dq];
    float4 r;
    r.x = cs.x + g0*((float)y0[0] - c0.x) + g1*((float)y1[0] - c1.x);
    r.y = cs.y + g0*((float)y0[1] - c0.y) + g1*((float)y1[1] - c1.y);
    r.z = cs.z + g0*((float)y0[2] - c0.z) + g1*((float)y1[2] - c1.z);
    r.w = cs.w + g0*((float)y0[3] - c0.w) + g1*((float)y1[3] - c1.w);
    ((float4*)out)[i] = r;
}

extern "C" void kernel_launch(void* const* d_in, const int* in_sizes, int n_in,
                              void* d_out, int out_size, void* d_ws, size_t ws_size,
                              hipStream_t stream){
    const float* x  = (const float*)d_in[0];
    const float* w1 = (const float*)d_in[1];
    const float* b1 = (const float*)d_in[2];
    const float* w2 = (const float*)d_in[3];
    const float* b2 = (const float*)d_in[4];
    const float* wr = (const float*)d_in[5];
    const float* br = (const float*)d_in[6];
    float* out = (float*)d_out;

    char* ws = (char*)d_ws;
    size_t o = 0;
    auto take = [&](size_t bytes)->char*{
        char* p = ws + o;
        o = (o + bytes + 255) & ~(size_t)255;
        return p;
    };
    _Float16* xb    = (_Float16*)take((size_t)N_TOK*DIM*2);        // 16.8 MB
    _Float16* w1t   = (_Float16*)take((size_t)NEXP*HID*DIM*2);     // 33.5 MB
    _Float16* w2t   = (_Float16*)take((size_t)NEXP*HID*DIM*2);     // 33.5 MB
    _Float16* hbuf  = (_Float16*)take((size_t)NSLOT*HID*2);        // 142.6 MB
    _Float16* ybuf  = (_Float16*)take((size_t)NSLOT*DIM*2);        // 35.7 MB
    float*    gb1   = (float*)take((size_t)NEXP*HID*4);
    float*    part  = (float*)take((size_t)NEXP*8*DIM*4);
    float*    cprime= (float*)take((size_t)NEXP*DIM*4);
    float*    csum  = (float*)take((size_t)DIM*4);
    int*      tbase = (int*)take(64);
    int*      expi  = (int*)take((size_t)N_TOK*2*4);
    float*    gatev = (float*)take((size_t)N_TOK*2*4);
    int*      slotof= (int*)take((size_t)N_TOK*2*4);
    int*      tokl  = (int*)take((size_t)NSLOT*4);
    (void)ws_size; (void)in_sizes; (void)n_in; (void)out_size;     // total ~263 MB

    hipFuncSetAttribute(reinterpret_cast<const void*>(&k_gemm8<DIM, HID, true>),
                        hipFuncAttributeMaxDynamicSharedMemorySize, 131072);
    hipFuncSetAttribute(reinterpret_cast<const void*>(&k_gemm8<HID, DIM, false>),
                        hipFuncAttributeMaxDynamicSharedMemorySize, 131072);

    hipLaunchKernelGGL(k_init, dim3((NSLOT+255)/256), dim3(256), 0, stream, tokl);
    hipLaunchKernelGGL(k_transpose, dim3(HID/32, DIM/32, NEXP), dim3(256), 0, stream, w1, w1t, DIM, HID);
    hipLaunchKernelGGL(k_transpose, dim3(DIM/32, HID/32, NEXP), dim3(256), 0, stream, w2, w2t, HID, DIM);
    hipLaunchKernelGGL(k_gb1, dim3(NEXP*HID/256), dim3(256), 0, stream, b1, gb1, NEXP*HID);
    hipLaunchKernelGGL(k_cprime_part, dim3(DIM/256, 8, NEXP), dim3(256), 0, stream, w2, gb1, part);
    hipLaunchKernelGGL(k_cfinal, dim3(DIM/256), dim3(256), 0, stream, part, b2, cprime, csum);
    hipLaunchKernelGGL(k_route, dim3(N_TOK/4), dim3(256), 0, stream, x, wr, br, xb, expi, gatev);
    hipLaunchKernelGGL(k_compact, dim3(NEXP), dim3(1024), 0, stream, expi, gatev, tbase, tokl, slotof);
    hipLaunchKernelGGL((k_gemm8<DIM, HID, true>), dim3(MAXT*(HID/256)), dim3(512), 131072, stream,
                       xb, w1t, b1, tokl, tbase, hbuf);
    hipLaunchKernelGGL((k_gemm8<HID, DIM, false>), dim3(MAXT*(DIM/256)), dim3(512), 131072, stream,
                       hbuf, w2t, b1, tokl, tbase, ybuf);
    hipLaunchKernelGGL(k_final, dim3(N_TOK*DIM/4/256), dim3(256), 0, stream,
                       expi, gatev, slotof, ybuf, cprime, csum, out);
}

// Round 8
// 499.965 us; speedup vs baseline: 2.0417x; 1.0398x over previous
//
#include <hip/hip_runtime.h>

#define N_TOK 8192
#define DIM   1024
#define HID   4096
#define NEXP  4
#define MAXT  68             // max 256-row m-tiles: 64 + 4 alignment pads
#define NSLOT (MAXT*256)

typedef __attribute__((ext_vector_type(8))) _Float16 f16x8;
typedef __attribute__((ext_vector_type(4))) _Float16 f16x4;
typedef __attribute__((ext_vector_type(4))) float    f32x4;

__device__ __forceinline__ float gelu_erf(float v){
    return 0.5f * v * (1.0f + erff(v * 0.70710678118654752440f));
}
__device__ __forceinline__ float gelu_tanh(float v){
    float u = 0.7978845608028654f * v * (1.0f + 0.044715f * v * v);
    float e = __expf(2.0f * u);
    float t = 1.0f - 2.0f / (e + 1.0f);
    return 0.5f * v * (1.0f + t);
}

#define GLDS16(g, s) __builtin_amdgcn_global_load_lds( \
    (const __attribute__((address_space(1))) void*)(g), \
    (__attribute__((address_space(3))) void*)(s), 16, 0, 0)

#define BARRIER() do{ __builtin_amdgcn_s_barrier(); __builtin_amdgcn_sched_barrier(0); }while(0)
#define VMCNTN(n) asm volatile("s_waitcnt vmcnt(" #n ")" ::: "memory")

// ---------------- fused transpose: w1 [E][D][H]->[E][H][D], w2 [E][H][D]->[E][D][H]
__global__ void k_transpose_all(const float* __restrict__ w1, const float* __restrict__ w2,
                                _Float16* __restrict__ w1t, _Float16* __restrict__ w2t){
    __shared__ float tile[32][33];
    int bid = blockIdx.x;            // 0..32767
    int z = bid >> 12;               // 8 slices of 4096 tiles
    int i = bid & 4095;
    const float* s; _Float16* d; int R, C, bx, by;
    if (z < 4){ R = DIM; C = HID; bx = i & 127; by = i >> 7;
        s = w1 + (size_t)z * R * C; d = w1t + (size_t)z * R * C; }
    else      { R = HID; C = DIM; bx = i & 31;  by = i >> 5;
        s = w2 + (size_t)(z-4) * R * C; d = w2t + (size_t)(z-4) * R * C; }
    int tx = threadIdx.x & 31, ty = threadIdx.x >> 5;   // 32 x 8
    int c0 = bx*32, r0 = by*32;
    #pragma unroll
    for (int rr = 0; rr < 32; rr += 8)
        tile[ty+rr][tx] = s[(size_t)(r0+ty+rr)*C + c0+tx];
    __syncthreads();
    #pragma unroll
    for (int rr = 0; rr < 32; rr += 8)
        d[(size_t)(c0+ty+rr)*R + r0+tx] = (_Float16)tile[tx][ty+rr];
}

// ---------------- gelu(b1) (erf form — must match reference c') -------------
__global__ void k_gb1(const float* __restrict__ b1, float* __restrict__ gb1, int n){
    int i = blockIdx.x*256 + threadIdx.x;
    if (i < n) gb1[i] = gelu_erf(b1[i]);
}

// ---------------- c' partials ----------------
__global__ void k_cprime_part(const float* __restrict__ w2, const float* __restrict__ gb1,
                              float* __restrict__ part){
    int d = blockIdx.x*256 + threadIdx.x;
    int p = blockIdx.y, e = blockIdx.z;
    float acc = 0.f;
    int h0 = p*(HID/8);
    for (int h = h0; h < h0 + HID/8; ++h)
        acc += gb1[e*HID + h] * w2[((size_t)e*HID + h)*DIM + d];
    part[(size_t)(e*8 + p)*DIM + d] = acc;
}

// ---------------- reduce partials -> cprime, csum ----------------
__global__ void k_cfinal(const float* __restrict__ part, const float* __restrict__ b2,
                         float* __restrict__ cprime, float* __restrict__ csum){
    int d = blockIdx.x*256 + threadIdx.x;
    float cs = 0.f;
    #pragma unroll
    for (int e = 0; e < NEXP; ++e){
        float a = 0.f;
        #pragma unroll
        for (int p = 0; p < 8; ++p) a += part[(size_t)(e*8 + p)*DIM + d];
        cprime[e*DIM + d] = a;
        cs += a + b2[e*DIM + d];
    }
    csum[d] = cs;
}

// ---------------- routing logits + x->f16 (atomic-free) ----------------
__global__ void k_route(const float* __restrict__ x, const float* __restrict__ wr,
                        const float* __restrict__ br, _Float16* __restrict__ xb,
                        int* __restrict__ expi, float* __restrict__ gatev){
    int lane = threadIdx.x & 63, w = threadIdx.x >> 6;
    int t = blockIdx.x*4 + w;
    const float4* x4  = (const float4*)(x + (size_t)t*DIM);
    const float4* wr4 = (const float4*)wr;
    f16x4* xb4 = (f16x4*)(xb + (size_t)t*DIM);
    float a0=0.f, a1=0.f, a2=0.f, a3=0.f;
    #pragma unroll
    for (int it = 0; it < 4; ++it){
        int q = it*64 + lane;
        float4 v = x4[q];
        f16x4 h; h[0]=(_Float16)v.x; h[1]=(_Float16)v.y; h[2]=(_Float16)v.z; h[3]=(_Float16)v.w;
        xb4[q] = h;
        int d = q*4;
        float4 w0 = wr4[d], w1v = wr4[d+1], w2v = wr4[d+2], w3v = wr4[d+3];
        a0 += v.x*w0.x + v.y*w1v.x + v.z*w2v.x + v.w*w3v.x;
        a1 += v.x*w0.y + v.y*w1v.y + v.z*w2v.y + v.w*w3v.y;
        a2 += v.x*w0.z + v.y*w1v.z + v.z*w2v.z + v.w*w3v.z;
        a3 += v.x*w0.w + v.y*w1v.w + v.z*w2v.w + v.w*w3v.w;
    }
    #pragma unroll
    for (int off = 32; off; off >>= 1){
        a0 += __shfl_xor(a0, off);
        a1 += __shfl_xor(a1, off);
        a2 += __shfl_xor(a2, off);
        a3 += __shfl_xor(a3, off);
    }
    if (lane == 0){
        float v[4] = {a0+br[0], a1+br[1], a2+br[2], a3+br[3]};
        int e0 = 0; float v0 = v[0];
        #pragma unroll
        for (int e = 1; e < 4; ++e) if (v[e] > v0){ v0 = v[e]; e0 = e; }
        int e1 = -1; float v1 = -1e30f;
        #pragma unroll
        for (int e = 0; e < 4; ++e) if (e != e0 && v[e] > v1){ v1 = v[e]; e1 = e; }
        float ex = expf(v1 - v0);
        float g0 = 1.f/(1.f+ex), g1 = ex/(1.f+ex);
        expi[2*t] = e0; expi[2*t+1] = e1;
        gatev[2*t] = g0; gatev[2*t+1] = g1;
    }
}

// ---------------- global compaction + pad fill ------------------------------
__global__ __launch_bounds__(1024)
void k_compact(const int* __restrict__ expi, const float* __restrict__ gatev,
               int* __restrict__ tbase, int* __restrict__ tokl, int* __restrict__ slotof){
    const int e = blockIdx.x;
    const int tid = threadIdx.x, lane = tid & 63, wv = tid >> 6;
    __shared__ int w4[16][4];
    __shared__ int wsum[16];
    int c0=0,c1=0,c2=0,c3=0;
    const int base = tid*16;
    #pragma unroll
    for (int i = 0; i < 16; ++i){
        int v = expi[base+i];
        c0 += (v==0); c1 += (v==1); c2 += (v==2); c3 += (v==3);
    }
    int mysel = (e==0)?c0:(e==1)?c1:(e==2)?c2:c3;
    int r0=c0, r1=c1, r2=c2, r3=c3;
    #pragma unroll
    for (int off = 32; off; off >>= 1){
        r0 += __shfl_xor(r0,off); r1 += __shfl_xor(r1,off);
        r2 += __shfl_xor(r2,off); r3 += __shfl_xor(r3,off);
    }
    if (lane == 0){ w4[wv][0]=r0; w4[wv][1]=r1; w4[wv][2]=r2; w4[wv][3]=r3; }
    int sc = mysel;
    #pragma unroll
    for (int off = 1; off < 64; off <<= 1){
        int tv = __shfl_up(sc, off);
        if (lane >= off) sc += tv;
    }
    if (lane == 63) wsum[wv] = sc;
    __syncthreads();
    int t0=0,t1=0,t2=0,t3=0;
    #pragma unroll
    for (int i = 0; i < 16; ++i){ t0+=w4[i][0]; t1+=w4[i][1]; t2+=w4[i][2]; t3+=w4[i][3]; }
    int n0=(t0+255)>>8, n1=(t1+255)>>8, n2=(t2+255)>>8, n3=(t3+255)>>8;
    int tb1=n0, tb2=n0+n1, tb3=n0+n1+n2, tb4=n0+n1+n2+n3;
    int mybase = ((e==0)?0:(e==1)?tb1:(e==2)?tb2:tb3)*256;
    int cnt_e  = (e==0)?t0:(e==1)?t1:(e==2)?t2:t3;
    int segrows= ((e==0)?n0:(e==1)?n1:(e==2)?n2:n3)*256;
    int wbase = 0;
    for (int i = 0; i < wv; ++i) wbase += wsum[i];
    int myoff = mybase + wbase + sc - mysel;
    #pragma unroll
    for (int i = 0; i < 16; ++i){
        int j = base + i;
        if (expi[j] == e){
            tokl[myoff]  = j >> 1;
            slotof[j] = myoff;
            myoff++;
        }
    }
    for (int i = cnt_e + tid; i < segrows; i += 1024) tokl[mybase + i] = 0;
    if (e == 0 && tid == 0){
        tbase[0]=0; tbase[1]=tb1; tbase[2]=tb2; tbase[3]=tb3; tbase[4]=tb4;
    }
}

// =================== GEMM1: 256x256x64, 4-phase, vmcnt(8)/tile ==============
// 512 thr = 8 waves (2M x 4N), per-wave 128x64. LDS buf q at q*65536:
// A[256][64] @0, B @+32768. Swizzle byte ^= (row&7)<<4 both-sides.
// Stages during tile t (all for t+2): P2:{A0,B0}(4) P3:{B1}(2) P4:{A1}(2).
// One sync pair per tile at P4: vmcnt(8) -> barrier confirms tile t+1's
// reads (staged in tile t-1) for ALL waves. Tail: vmcnt(0).

#define MFMA_Q(RA, RB, MB, NB) \
  _Pragma("unroll") for (int mf_ = 0; mf_ < 4; ++mf_) \
    _Pragma("unroll") for (int nf_ = 0; nf_ < 2; ++nf_) \
      _Pragma("unroll") for (int ks_ = 0; ks_ < 2; ++ks_) \
        acc[MB+mf_][NB+nf_] = __builtin_amdgcn_mfma_f32_16x16x32_f16( \
            RA[mf_][ks_], RB[nf_][ks_], acc[MB+mf_][NB+nf_], 0, 0, 0)

#define LDA_HALF(DST, MB, CUR) \
  _Pragma("unroll") for (int mf_ = 0; mf_ < 4; ++mf_) \
    _Pragma("unroll") for (int ks_ = 0; ks_ < 2; ++ks_) \
      DST[mf_][ks_] = *(const f16x8*)(smem + (CUR)*65536 + (rbA[MB+mf_] ^ (ks_<<6)))

#define LDB_HALF(DST, NB, CUR) \
  _Pragma("unroll") for (int nf_ = 0; nf_ < 2; ++nf_) \
    _Pragma("unroll") for (int ks_ = 0; ks_ < 2; ++ks_) \
      DST[nf_][ks_] = *(const f16x8*)(smem + (CUR)*65536 + (rbB[NB+nf_] ^ (ks_<<6)))

#define STAGE_A(Q, KTN, H) do{ \
    GLDS16(pA[0][H] + (size_t)(KTN)*64, smem + (Q)*65536 + dstA[0][H]); \
    GLDS16(pA[1][H] + (size_t)(KTN)*64, smem + (Q)*65536 + dstA[1][H]); }while(0)
#define STAGE_B(Q, KTN, H) do{ \
    GLDS16(pB[0][H] + (size_t)(KTN)*64, smem + (Q)*65536 + 32768 + dstB[0][H]); \
    GLDS16(pB[1][H] + (size_t)(KTN)*64, smem + (Q)*65536 + 32768 + dstB[1][H]); }while(0)

__global__ __launch_bounds__(512, 2)
void k_gemm1d(const _Float16* __restrict__ Aglob, const _Float16* __restrict__ Bglob,
              const float* __restrict__ b1, const int* __restrict__ tokl,
              const int* __restrict__ tb, _Float16* __restrict__ Cout)
{
    extern __shared__ char smem[];
    const int NT = HID/256;                      // 16
    const int nwg = MAXT*NT;                     // 1088
    const int logical = ((int)blockIdx.x & 7)*(nwg>>3) + ((int)blockIdx.x >> 3);
    const int mt = logical / NT, nt = logical % NT;
    if (mt >= tb[4]) return;
    const int e = (mt >= tb[1]) + (mt >= tb[2]) + (mt >= tb[3]);
    const int tid = (int)threadIdx.x;
    const int ln = tid & 63, wv = tid >> 6;
    const int wr2 = wv >> 2, wc4 = wv & 3;
    const int lr = ln & 15, lk = ln >> 4;
    const int NK = DIM/64;                       // 16

    const _Float16* pA[2][2]; const _Float16* pB[2][2];
    int dstA[2][2], dstB[2][2];
    #pragma unroll
    for (int l = 0; l < 2; ++l)
      #pragma unroll
      for (int h = 0; h < 2; ++h){
        const int ch   = wv*2 + l;
        const int flat = ch*64 + ln;
        const int lr_  = flat >> 3;
        const int c    = flat & 7;
        const int csw  = (c ^ (lr_ & 7)) * 8;
        const int rowA = (lr_ & 63) + ((lr_ >> 6) << 7) + h*64;
        const int rowB = (lr_ & 31) + ((lr_ >> 5) << 6) + h*32;
        size_t arow = (size_t)tokl[mt*256 + rowA];
        pA[l][h] = Aglob + arow*DIM + csw;
        pB[l][h] = Bglob + ((size_t)e*HID + nt*256 + rowB)*DIM + csw;
        const int lrs = ch*8;
        dstA[l][h] = ((lrs & 63) + ((lrs >> 6) << 7) + h*64) * 128;
        dstB[l][h] = ((lrs & 31) + ((lrs >> 5) << 6) + h*32) * 128;
      }

    int rbA[8], rbB[4];
    #pragma unroll
    for (int mf = 0; mf < 8; ++mf){
        int row = wr2*128 + mf*16 + lr;
        rbA[mf] = row*128 + ((lk*16) ^ ((row&7)<<4));
    }
    #pragma unroll
    for (int nf = 0; nf < 4; ++nf){
        int row = wc4*64 + nf*16 + lr;
        rbB[nf] = 32768 + row*128 + ((lk*16) ^ ((row&7)<<4));
    }

    f32x4 acc[8][4];
    #pragma unroll
    for (int i = 0; i < 8; ++i)
        #pragma unroll
        for (int j = 0; j < 4; ++j) acc[i][j] = (f32x4){0.f,0.f,0.f,0.f};
    f16x8 rA0[4][2], rA1[4][2], rB0[2][2], rB1[2][2];

    // prologue: tiles 0 and 1 fully (16 loads); confirm tile 0 before loop
    STAGE_A(0,0,0); STAGE_B(0,0,0); STAGE_B(0,0,1); STAGE_A(0,0,1);
    STAGE_A(1,1,0); STAGE_B(1,1,0); STAGE_B(1,1,1); STAGE_A(1,1,1);
    VMCNTN(8);
    BARRIER();

    for (int t = 0; t < NK; ++t){
        const int cur = t & 1;
        // P1: read A0,B0 (confirmed by previous tile's pair)
        LDA_HALF(rA0, 0, cur); LDB_HALF(rB0, 0, cur);
        BARRIER();
        __builtin_amdgcn_s_setprio(1); MFMA_Q(rA0, rB0, 0, 0); __builtin_amdgcn_s_setprio(0);
        BARRIER();
        // P2: read B1 | stage A0,B0 of t+2 -> cur (region read at P1)
        LDB_HALF(rB1, 2, cur);
        if (t+2 < NK){ STAGE_A(cur, t+2, 0); STAGE_B(cur, t+2, 0); }
        BARRIER();
        __builtin_amdgcn_s_setprio(1); MFMA_Q(rA0, rB1, 0, 2); __builtin_amdgcn_s_setprio(0);
        BARRIER();
        // P3: read A1 | stage B1 of t+2 -> cur (region read at P2)
        LDA_HALF(rA1, 4, cur);
        if (t+2 < NK) STAGE_B(cur, t+2, 1);
        BARRIER();
        __builtin_amdgcn_s_setprio(1); MFMA_Q(rA1, rB1, 4, 2); __builtin_amdgcn_s_setprio(0);
        BARRIER();
        // P4: stage A1 of t+2 -> cur (region read at P3) | SYNC PAIR
        if (t+2 < NK){ STAGE_A(cur, t+2, 1); VMCNTN(8); } else { VMCNTN(0); }
        BARRIER();
        __builtin_amdgcn_s_setprio(1); MFMA_Q(rA1, rB0, 4, 0); __builtin_amdgcn_s_setprio(0);
        BARRIER();
    }

    float bv[4];
    #pragma unroll
    for (int nf = 0; nf < 4; ++nf)
        bv[nf] = b1[e*HID + nt*256 + wc4*64 + nf*16 + lr];
    #pragma unroll
    for (int mf = 0; mf < 8; ++mf){
        int row = mt*256 + wr2*128 + mf*16 + lk*4;
        #pragma unroll
        for (int nf = 0; nf < 4; ++nf){
            int col = nt*256 + wc4*64 + nf*16 + lr;
            #pragma unroll
            for (int r = 0; r < 4; ++r)
                Cout[(size_t)(row+r)*HID + col] = (_Float16)gelu_tanh(acc[mf][nf][r] + bv[nf]);
        }
    }
}

// =================== GEMM2: 128x256x64, 2-phase, two pairs/tile =============
// 512 thr = 8 waves (2M x 4N), per-wave 64x64. LDS buf q at q*49152:
// A[128][64] @0 (16KB), B[256][64] @+16384 (32KB). 96KB total.
// P1: read A,B0(t) | stage B1(t+1)->nxt   | vmcnt(6)->bar | MFMA q0 | bar
// P2: read B1(t)   | stage A,B0(t+2)->cur | vmcnt(6)->bar | MFMA q1 | bar
// Each pair confirms the NEXT phase's reads for all waves (FIFO-verified).
// Tails: P1 t=NK-1: 0; P2 t=NK-2: 2, t=NK-1: 0.

#define G2_LDA(CUR) \
  _Pragma("unroll") for (int mf_ = 0; mf_ < 4; ++mf_) \
    _Pragma("unroll") for (int ks_ = 0; ks_ < 2; ++ks_) \
      rA[mf_][ks_] = *(const f16x8*)(smem + (CUR)*49152 + (rbA[mf_] ^ (ks_<<6)))

#define G2_LDB(DST, NB, CUR) \
  _Pragma("unroll") for (int nf_ = 0; nf_ < 2; ++nf_) \
    _Pragma("unroll") for (int ks_ = 0; ks_ < 2; ++ks_) \
      DST[nf_][ks_] = *(const f16x8*)(smem + (CUR)*49152 + (rbB[NB+nf_] ^ (ks_<<6)))

#define G2_STAGE_A(Q, KTN) do{ \
    GLDS16(pA[0] + (size_t)(KTN)*64, smem + (Q)*49152 + dstA[0]); \
    GLDS16(pA[1] + (size_t)(KTN)*64, smem + (Q)*49152 + dstA[1]); }while(0)
#define G2_STAGE_B(Q, KTN, H) do{ \
    GLDS16(pB[0][H] + (size_t)(KTN)*64, smem + (Q)*49152 + 16384 + dstB[0][H]); \
    GLDS16(pB[1][H] + (size_t)(KTN)*64, smem + (Q)*49152 + 16384 + dstB[1][H]); }while(0)

__global__ __launch_bounds__(512, 2)
void k_gemm2d(const _Float16* __restrict__ hbuf, const _Float16* __restrict__ w2t,
              const int* __restrict__ tb, _Float16* __restrict__ ybuf)
{
    extern __shared__ char smem[];
    const int NT = DIM/256;                      // 4
    const int nwg = 2*MAXT*NT;                   // 544
    const int logical = ((int)blockIdx.x & 7)*(nwg>>3) + ((int)blockIdx.x >> 3);
    const int mt = logical / NT, nt = logical % NT;
    if (mt >= 2*tb[4]) return;
    const int e = (mt >= 2*tb[1]) + (mt >= 2*tb[2]) + (mt >= 2*tb[3]);
    const int tid = (int)threadIdx.x;
    const int ln = tid & 63, wv = tid >> 6;
    const int wr2 = wv >> 2, wc4 = wv & 3;
    const int lr = ln & 15, lk = ln >> 4;
    const int NK = HID/64;                       // 64

    const _Float16* pA[2]; int dstA[2];
    const _Float16* pB[2][2]; int dstB[2][2];
    #pragma unroll
    for (int l = 0; l < 2; ++l){
        const int ch   = wv*2 + l;
        const int flat = ch*64 + ln;
        const int lr_  = flat >> 3;              // 0..127
        const int c    = flat & 7;
        const int csw  = (c ^ (lr_ & 7)) * 8;
        pA[l] = hbuf + ((size_t)mt*128 + lr_)*HID + csw;
        dstA[l] = (ch*8)*128;
        #pragma unroll
        for (int h = 0; h < 2; ++h){
            const int rowB = (lr_ & 31) + ((lr_ >> 5) << 6) + h*32;
            pB[l][h] = w2t + ((size_t)e*DIM + nt*256 + rowB)*HID + csw;
            const int lrs = ch*8;
            dstB[l][h] = ((lrs & 31) + ((lrs >> 5) << 6) + h*32) * 128;
        }
    }

    int rbA[4], rbB[4];
    #pragma unroll
    for (int mf = 0; mf < 4; ++mf){
        int row = wr2*64 + mf*16 + lr;
        rbA[mf] = row*128 + ((lk*16) ^ ((row&7)<<4));
    }
    #pragma unroll
    for (int nf = 0; nf < 4; ++nf){
        int row = wc4*64 + nf*16 + lr;
        rbB[nf] = 16384 + row*128 + ((lk*16) ^ ((row&7)<<4));
    }

    f32x4 acc[4][4];
    #pragma unroll
    for (int i = 0; i < 4; ++i)
        #pragma unroll
        for (int j = 0; j < 4; ++j) acc[i][j] = (f32x4){0.f,0.f,0.f,0.f};
    f16x8 rA[4][2], rB0[2][2], rB1[2][2];

    // prologue FIFO: {A,B0}(0) x4, {B1}(0) x2, {A,B0}(1) x4; confirm {A,B0}(0)
    G2_STAGE_A(0,0); G2_STAGE_B(0,0,0);
    G2_STAGE_B(0,0,1);
    G2_STAGE_A(1,1); G2_STAGE_B(1,1,0);
    VMCNTN(6);
    BARRIER();

    for (int t = 0; t < NK; ++t){
        const int cur = t & 1;
        // P1: read A,B0(t); stage B1(t+1) -> cur^1; SYNC PAIR confirms B1(t)
        G2_LDA(cur); G2_LDB(rB0, 0, cur);
        if (t+1 < NK){ G2_STAGE_B(cur^1, t+1, 1); VMCNTN(6); } else { VMCNTN(0); }
        BARRIER();
        __builtin_amdgcn_s_setprio(1); MFMA_Q(rA, rB0, 0, 0); __builtin_amdgcn_s_setprio(0);
        BARRIER();
        // P2: read B1(t); stage A,B0(t+2) -> cur; SYNC PAIR confirms A,B0(t+1)
        G2_LDB(rB1, 2, cur);
        if (t+2 < NK){ G2_STAGE_A(cur, t+2); G2_STAGE_B(cur, t+2, 0); VMCNTN(6); }
        else if (t+1 < NK){ VMCNTN(2); }
        else { VMCNTN(0); }
        BARRIER();
        __builtin_amdgcn_s_setprio(1); MFMA_Q(rA, rB1, 0, 2); __builtin_amdgcn_s_setprio(0);
        BARRIER();
    }

    #pragma unroll
    for (int mf = 0; mf < 4; ++mf){
        int row = mt*128 + wr2*64 + mf*16 + lk*4;
        #pragma unroll
        for (int nf = 0; nf < 4; ++nf){
            int col = nt*256 + wc4*64 + nf*16 + lr;
            #pragma unroll
            for (int r = 0; r < 4; ++r)
                ybuf[(size_t)(row+r)*DIM + col] = (_Float16)acc[mf][nf][r];
        }
    }
}

// ---------------- final: out = csum + g0*(y0-c'0) + g1*(y1-c'1) -------------
__global__ void k_final(const int* __restrict__ expi, const float* __restrict__ gatev,
                        const int* __restrict__ slotof, const _Float16* __restrict__ ybuf,
                        const float* __restrict__ cprime, const float* __restrict__ csum,
                        float* __restrict__ out){
    int i = blockIdx.x*256 + threadIdx.x;
    int t = i >> 8;
    int dq = i & 255;
    int e0 = expi[2*t], e1 = expi[2*t+1];
    float g0 = gatev[2*t], g1 = gatev[2*t+1];
    int s0 = slotof[2*t], s1 = slotof[2*t+1];
    const float4* cp = (const float4*)cprime;
    float4 cs = ((const float4*)csum)[dq];
    float4 c0 = cp[e0*256 + dq], c1 = cp[e1*256 + dq];
    f16x4 y0 = ((const f16x4*)ybuf)[(size_t)s0*256 + dq];
    f16x4 y1 = ((const f16x4*)ybuf)[(size_t)s1*256 + dq];
    float4 r;
    r.x = cs.x + g0*((float)y0[0] - c0.x) + g1*((float)y1[0] - c1.x);
    r.y = cs.y + g0*((float)y0[1] - c0.y) + g1*((float)y1[1] - c1.y);
    r.z = cs.z + g0*((float)y0[2] - c0.z) + g1*((float)y1[2] - c1.z);
    r.w = cs.w + g0*((float)y0[3] - c0.w) + g1*((float)y1[3] - c1.w);
    ((float4*)out)[i] = r;
}

extern "C" void kernel_launch(void* const* d_in, const int* in_sizes, int n_in,
                              void* d_out, int out_size, void* d_ws, size_t ws_size,
                              hipStream_t stream){
    const float* x  = (const float*)d_in[0];
    const float* w1 = (const float*)d_in[1];
    const float* b1 = (const float*)d_in[2];
    const float* w2 = (const float*)d_in[3];
    const float* b2 = (const float*)d_in[4];
    const float* wr = (const float*)d_in[5];
    const float* br = (const float*)d_in[6];
    float* out = (float*)d_out;

    char* ws = (char*)d_ws;
    size_t o = 0;
    auto take = [&](size_t bytes)->char*{
        char* p = ws + o;
        o = (o + bytes + 255) & ~(size_t)255;
        return p;
    };
    _Float16* xb    = (_Float16*)take((size_t)N_TOK*DIM*2);        // 16.8 MB
    _Float16* w1t   = (_Float16*)take((size_t)NEXP*HID*DIM*2);     // 33.5 MB
    _Float16* w2t   = (_Float16*)take((size_t)NEXP*HID*DIM*2);     // 33.5 MB
    _Float16* hbuf  = (_Float16*)take((size_t)NSLOT*HID*2);        // 142.6 MB
    _Float16* ybuf  = (_Float16*)take((size_t)NSLOT*DIM*2);        // 35.7 MB
    float*    gb1   = (float*)take((size_t)NEXP*HID*4);
    float*    part  = (float*)take((size_t)NEXP*8*DIM*4);
    float*    cprime= (float*)take((size_t)NEXP*DIM*4);
    float*    csum  = (float*)take((size_t)DIM*4);
    int*      tbase = (int*)take(64);
    int*      expi  = (int*)take((size_t)N_TOK*2*4);
    float*    gatev = (float*)take((size_t)N_TOK*2*4);
    int*      slotof= (int*)take((size_t)N_TOK*2*4);
    int*      tokl  = (int*)take((size_t)NSLOT*4);
    (void)ws_size; (void)in_sizes; (void)n_in; (void)out_size;

    hipFuncSetAttribute(reinterpret_cast<const void*>(&k_gemm1d),
                        hipFuncAttributeMaxDynamicSharedMemorySize, 131072);
    hipFuncSetAttribute(reinterpret_cast<const void*>(&k_gemm2d),
                        hipFuncAttributeMaxDynamicSharedMemorySize, 98304);

    hipLaunchKernelGGL(k_transpose_all, dim3(32768), dim3(256), 0, stream, w1, w2, w1t, w2t);
    hipLaunchKernelGGL(k_gb1, dim3(NEXP*HID/256), dim3(256), 0, stream, b1, gb1, NEXP*HID);
    hipLaunchKernelGGL(k_cprime_part, dim3(DIM/256, 8, NEXP), dim3(256), 0, stream, w2, gb1, part);
    hipLaunchKernelGGL(k_cfinal, dim3(DIM/256), dim3(256), 0, stream, part, b2, cprime, csum);
    hipLaunchKernelGGL(k_route, dim3(N_TOK/4), dim3(256), 0, stream, x, wr, br, xb, expi, gatev);
    hipLaunchKernelGGL(k_compact, dim3(NEXP), dim3(1024), 0, stream, expi, gatev, tbase, tokl, slotof);
    hipLaunchKernelGGL(k_gemm1d, dim3(MAXT*(HID/256)), dim3(512), 131072, stream,
                       xb, w1t, b1, tokl, tbase, hbuf);
    hipLaunchKernelGGL(k_gemm2d, dim3(2*MAXT*(DIM/256)), dim3(512), 98304, stream,
                       hbuf, w2t, tbase, ybuf);
    hipLaunchKernelGGL(k_final, dim3(N_TOK*DIM/4/256), dim3(256), 0, stream,
                       expi, gatev, slotof, ybuf, cprime, csum, out);
}